// Round 6
// baseline (203.660 us; speedup 1.0000x reference)
//
#include <hip/hip_runtime.h>
#include <math.h>

typedef __attribute__((ext_vector_type(8))) short short8;
typedef __attribute__((ext_vector_type(4))) float floatx4;

__device__ __forceinline__ unsigned short bf16r(float f) {
  union { float f; unsigned int u; } v; v.f = f;
  unsigned int u = v.u;
  return (unsigned short)((u + 0x7fffu + ((u >> 16) & 1u)) >> 16);
}
// round-half-up pack (sampling path; 2 ops)
__device__ __forceinline__ unsigned int bf16h(float f) {
  union { float f; unsigned int u; } v; v.f = f;
  return (v.u + 0x8000u) >> 16;
}
__device__ __forceinline__ float bf2f(unsigned int u) {
  union { unsigned int u; float f; } v; v.u = u << 16; return v.f;
}
// async global->LDS DMA, 16B/lane; LDS dst = wave-uniform base + lane*16
__device__ __forceinline__ void glds16(const void* g, void* l) {
  __builtin_amdgcn_global_load_lds(
      (const __attribute__((address_space(1))) unsigned int*)g,
      (__attribute__((address_space(3))) unsigned int*)l, 16, 0, 0);
}

// ---------------------------------------------------------------------------
// K0 (MERGED prep + xT): weight prep (bf16, lane-linear MFMA-frag layouts),
// fused tables, w_off-nonzero flags, and the x->xT transpose.
// ---------------------------------------------------------------------------
__global__ __launch_bounds__(256) void k_pre(
    const float* __restrict__ x,
    const float* __restrict__ w_dcn, const float* __restrict__ w_off,
    const float* __restrict__ b_dcn,
    const float* __restrict__ bn_g, const float* __restrict__ bn_b,
    const float* __restrict__ bn_m, const float* __restrict__ bn_v,
    const float* __restrict__ w_up, const float* __restrict__ w1x1,
    unsigned short* __restrict__ xT,
    unsigned short* __restrict__ wt_dcn, unsigned short* __restrict__ wt_off,
    float* __restrict__ vtab, float* __restrict__ bntab,
    unsigned int* __restrict__ offflags) {
  __shared__ unsigned short sx[32 * 264];
  int e = blockIdx.x * 256 + threadIdx.x;
  if (e < 294912) {
    int s = e >> 12;            // s = cg*9 + k  (72 tiles of 4096 ush)
    int r = e & 4095;
    int ot = r >> 9;            // 8 output-tiles of 512 ush
    int lane = (r >> 3) & 63;   // wave lane this element feeds
    int j = e & 7;
    int l15 = lane & 15, quad = lane >> 4;
    int o = ot * 16 + l15;
    int k = s % 9, cg = s / 9;
    int c = cg * 32 + quad * 8 + j;
    wt_dcn[e] = bf16r(w_dcn[(o * 256 + c) * 9 + k]);
  }
  bool nz = false;
  if (e < 73728) {
    int cg = e / 9216;
    int r = e % 9216;
    int frag = r >> 9;          // 18 frags: (k,ot)
    int k = frag >> 1, ot = frag & 1;
    int lane = (r >> 3) & 63, j = e & 7;
    int l15 = lane & 15, quad = lane >> 4;
    int oc = ot * 16 + l15;
    int c = cg * 32 + quad * 8 + j;
    float wv = (oc < 27) ? w_off[(oc * 256 + c) * 9 + k] : 0.f;
    wt_off[e] = bf16r(wv);
    nz = (wv != 0.f);
  }
  unsigned long long ba = __ballot(nz);
  if (blockIdx.x < 288 && (threadIdx.x & 63) == 0)
    offflags[blockIdx.x * 4 + (threadIdx.x >> 6)] = (ba != 0ull) ? 1u : 0u;
  if (e < 2048) {
    int o = e >> 4;
    vtab[e] = w1x1[o] * w_up[e];
  }
  if (e < 128) {
    float g = bn_g[e] * rsqrtf(bn_v[e] + 1e-5f);
    bntab[e] = g;
    bntab[128 + e] = (b_dcn[e] - bn_m[e]) * g + bn_b[e];
  }
  if (blockIdx.x < 1024) {
    int b = blockIdx.x & 7, px0 = ((blockIdx.x >> 3) & 127) * 32;
    int t = threadIdx.x;
    int px = t & 31, cg = t >> 5;
    const float* xsrc = x + (((size_t)(b * 256 + cg * 32)) << 12) + px0 + px;
#pragma unroll
    for (int cc = 0; cc < 32; ++cc)
      sx[px * 264 + cg * 32 + cc] = bf16r(xsrc[(size_t)cc << 12]);
    __syncthreads();
#pragma unroll
    for (int j = 0; j < 4; ++j) {
      int unit = t + j * 256;
      int p = unit >> 5, chunk = unit & 31;
      uint4 v = *(const uint4*)&sx[p * 264 + chunk * 8];
      *(uint4*)&xT[((size_t)((b << 12) + px0 + p)) * 256 + chunk * 8] = v;
    }
  }
}

// ---------------------------------------------------------------------------
// K2 (FUSED, 512-thr ROW-PAIR blocks): offset-conv + DCNv2 MFMA + BN/ReLU +
// fused (upsample x 1x1) -> R.
// grid 256 = (b, row-pair); 8 waves/block: wave wvx -> row = row0 + (wvx>>2),
// px = (wvx&3)*16 + l15.  W staging (24 KB/phase glds) shared by both rows
// -> W fetch halves; waves/CU 8 -> 16 (TLP doubles).
// Tap tables live in REGISTERS (each thread only needs its own px's 9 taps);
// the phase loop is unrolled x3 so all tap indices are compile-time.
// FAST PATH (w_off==0): om = b_off exactly; prologue-A skipped; block's xT
// neighborhood L2-warmed by linear keep-alive reads (replaces the warming
// side-effect prologue-A's gathers used to provide -- R5's +24us was cold xT).
// XCD-swizzled: batch b -> XCD b.
// ---------------------------------------------------------------------------
__global__ __launch_bounds__(512, 2) void k_dcn(
    const unsigned short* __restrict__ xT, const unsigned short* __restrict__ wt,
    const unsigned short* __restrict__ wtoff, const float* __restrict__ b_off,
    const float* __restrict__ vtab, const float* __restrict__ bntab,
    const unsigned int* __restrict__ offflags, float* __restrict__ R) {
  int b = blockIdx.x & 7, row0 = (blockIdx.x >> 3) * 2;
  __shared__ unsigned short sW[2 * 12288];   // 48 KB (dbuf W / prologue-A / epi)
  __shared__ unsigned int s_fl[8];
  int t = threadIdx.x, lane = t & 63, wvx = t >> 6;
  int l15 = lane & 15, quad = lane >> 4;
  int row_local = wvx >> 2, wv4 = wvx & 3;
  int row = row0 + row_local;
  int px = wv4 * 16 + l15;
  const unsigned short* xb = xT + (((size_t)b) << 12) * 256;
  const short8 zz = {0, 0, 0, 0, 0, 0, 0, 0};
  // som (slow path): 2 rows x 27 x 64 bf16 at ush offset 18432 (above the
  // 2x9216 prologue-A buffers; dies before phase-1 staging touches buf1)
  unsigned short* som = (unsigned short*)sW + 18432;

  // ---- w_off-nonzero flag (grid-uniform) ----------------------------------
  {
    unsigned int a = 0;
    for (int i = t; i < 1152; i += 512) a |= offflags[i];
    a = __any(a != 0u) ? 1u : 0u;
    if (lane == 0) s_fl[wvx] = a;
  }
  __syncthreads();
  unsigned int fl = 0;
#pragma unroll
  for (int i = 0; i < 8; ++i) fl |= s_fl[i];
  const bool offnz = fl != 0u;

  if (!offnz) {
    // FAST PATH warming: linear sweep of this block's 4 xT rows into home L2
    int wr0 = max(row0 - 1, 0), wr1 = min(row0 + 2, 63);
    for (int rr = wr0; rr <= wr1; ++rr) {
      const uint4* src = (const uint4*)(xb + ((size_t)(rr << 6)) * 256);
#pragma unroll
      for (int i = 0; i < 4; ++i) {
        uint4 v = src[t + (i << 9)];
        asm volatile("" :: "v"(v.x), "v"(v.y), "v"(v.z), "v"(v.w));
      }
    }
  } else {
    // ---- prologue-A (slow path): offset conv for both rows ----------------
    int pixk[9]; bool vkk[9];
#pragma unroll
    for (int k = 0; k < 9; ++k) {
      int yy = row + k / 3 - 1, xx = px + k % 3 - 1;
      vkk[k] = ((unsigned)yy < 64u) & ((unsigned)xx < 64u);
      pixk[k] = vkk[k] ? (yy * 64 + xx) : 0;
    }
    floatx4 oacc[2];
    oacc[0] = (floatx4){0.f, 0.f, 0.f, 0.f};
    oacc[1] = (floatx4){0.f, 0.f, 0.f, 0.f};
#pragma unroll
    for (int i = 0; i < 3; ++i) {
      int frag = wvx + i * 8;
      if (frag < 18)
        glds16(wtoff + (size_t)frag * 512 + lane * 8, &sW[frag * 512]);
    }
    __syncthreads();
    for (int cg = 0; cg < 8; ++cg) {
      unsigned short* buf = sW + (cg & 1) * 9216;
      int cb = cg * 32 + quad * 8;
      short8 bx[9];
#pragma unroll
      for (int k = 0; k < 9; ++k) {
        short8 v = *(const short8*)&xb[(size_t)pixk[k] * 256 + cb];
        bx[k] = vkk[k] ? v : zz;
      }
      if (cg < 7) {
        const unsigned short* wsrc = wtoff + (size_t)(cg + 1) * 9216;
        unsigned short* nbuf = sW + ((cg + 1) & 1) * 9216;
#pragma unroll
        for (int i = 0; i < 3; ++i) {
          int frag = wvx + i * 8;
          if (frag < 18)
            glds16(wsrc + (size_t)frag * 512 + lane * 8, &nbuf[frag * 512]);
        }
      }
#pragma unroll
      for (int k = 0; k < 9; ++k) {
        short8 a0 = *(const short8*)&buf[(k * 2 + 0) * 512 + lane * 8];
        short8 a1 = *(const short8*)&buf[(k * 2 + 1) * 512 + lane * 8];
        oacc[0] = __builtin_amdgcn_mfma_f32_16x16x32_bf16(a0, bx[k], oacc[0], 0, 0, 0);
        oacc[1] = __builtin_amdgcn_mfma_f32_16x16x32_bf16(a1, bx[k], oacc[1], 0, 0, 0);
      }
      __syncthreads();
    }
#pragma unroll
    for (int ot = 0; ot < 2; ++ot)
#pragma unroll
      for (int r = 0; r < 4; ++r) {
        int o = ot * 16 + quad * 4 + r;
        if (o < 27) som[row_local * 1728 + o * 64 + px] = bf16r(oacc[ot][r] + b_off[o]);
      }
    __syncthreads();   // som complete
  }

  // ---- prologue-B: this thread's 9 taps -> REGISTERS ----------------------
  ushort4 tir[9]; float4 twr[9];
  {
    const unsigned short* smr = som + row_local * 1728;
#pragma unroll
    for (int k = 0; k < 9; ++k) {
      float o1, o2, mv;
      if (offnz) {
        o1 = bf2f(smr[k * 64 + px]);
        o2 = bf2f(smr[(9 + k) * 64 + px]);
        mv = bf2f(smr[(18 + k) * 64 + px]);
      } else {
        o1 = bf2f(bf16r(b_off[k]));          // == bf16r(0 + b_off)
        o2 = bf2f(bf16r(b_off[9 + k]));
        mv = bf2f(bf16r(b_off[18 + k]));
      }
      float m = 1.f / (1.f + __expf(-mv));
      float py = (float)(row + k / 3 - 1) + o1;
      float pxf = (float)(px + (k % 3) - 1) + o2;
      float fy = floorf(py), fx = floorf(pxf);
      int iy = (int)fy, ix = (int)fx;
      float wy1 = py - fy, wy0 = 1.f - wy1;
      float wx1 = pxf - fx, wx0 = 1.f - wx1;
      bool y0ok = (iy >= 0) & (iy < 64), y1ok = (iy >= -1) & (iy < 63);
      bool x0ok = (ix >= 0) & (ix < 64), x1ok = (ix >= -1) & (ix < 63);
      int iy0 = min(max(iy, 0), 63), iy1 = min(max(iy + 1, 0), 63);
      int ix0 = min(max(ix, 0), 63), ix1 = min(max(ix + 1, 0), 63);
      tir[k] = make_ushort4((unsigned short)(iy0 * 64 + ix0), (unsigned short)(iy0 * 64 + ix1),
                            (unsigned short)(iy1 * 64 + ix0), (unsigned short)(iy1 * 64 + ix1));
      float4 w;
      w.x = (y0ok && x0ok) ? m * wy0 * wx0 : 0.f;
      w.y = (y0ok && x1ok) ? m * wy0 * wx1 : 0.f;
      w.z = (y1ok && x0ok) ? m * wy1 * wx0 : 0.f;
      w.w = (y1ok && x1ok) ? m * wy1 * wx1 : 0.f;
      twr[k] = w;
    }
  }

  const uint4 z4 = make_uint4(0u, 0u, 0u, 0u);
  floatx4 acc[8];
#pragma unroll
  for (int i = 0; i < 8; ++i) acc[i] = (floatx4){0.f, 0.f, 0.f, 0.f};

  // phase-0 tap prefetch (k = kk, static)
  uint4 traw[12];
  {
    int cbase = quad * 8;
#pragma unroll
    for (int kk = 0; kk < 3; ++kk) {
      ushort4 ti = tir[kk]; float4 twn = twr[kk];
      uint4 t0 = z4, t1 = z4, t2 = z4, t3 = z4;
      if (__any(twn.x != 0.f)) t0 = *(const uint4*)&xb[(size_t)ti.x * 256 + cbase];
      if (__any(twn.y != 0.f)) t1 = *(const uint4*)&xb[(size_t)ti.y * 256 + cbase];
      if (__any(twn.z != 0.f)) t2 = *(const uint4*)&xb[(size_t)ti.z * 256 + cbase];
      if (__any(twn.w != 0.f)) t3 = *(const uint4*)&xb[(size_t)ti.w * 256 + cbase];
      traw[kk * 4 + 0] = t0; traw[kk * 4 + 1] = t1;
      traw[kk * 4 + 2] = t2; traw[kk * 4 + 3] = t3;
    }
  }
  {  // glds W(phase 0) -> buf 0 (3 blks per wave, 24 total)
#pragma unroll
    for (int i = 0; i < 3; ++i) {
      int blk = wvx * 3 + i;
      glds16(wt + (size_t)blk * 512 + lane * 8, &sW[blk * 512]);
    }
  }
  __syncthreads();   // buf0 complete + taps/som reads all done

  // ---- main loop: 24 phases, unrolled x3 so tap indices are static --------
  for (int p3 = 0; p3 < 8; ++p3) {
#pragma unroll
    for (int sub = 0; sub < 3; ++sub) {
      int phase = p3 * 3 + sub;
      unsigned short* buf = sW + (phase & 1) * 12288;
      unsigned short* nbuf = sW + ((phase + 1) & 1) * 12288;
      bool notlast = (sub < 2) | (p3 < 7);
      if (notlast) {
        const unsigned short* wsrc = wt + (size_t)(phase + 1) * 12288;
#pragma unroll
        for (int i = 0; i < 3; ++i) {
          int blk = wvx * 3 + i;
          glds16(wsrc + (size_t)blk * 512 + lane * 8, &nbuf[blk * 512]);
        }
      }
      int cgn = (sub == 2) ? (p3 + 1) : p3;
      int ncbase = cgn * 32 + quad * 8;

#pragma unroll
      for (int kk = 0; kk < 3; ++kk) {
        const int k = sub * 3 + kk;                 // static
        float4 tw = twr[k];
        union { uint4 u; short8 s; } x0, x1, x2, x3;
        x0.u = traw[kk * 4 + 0]; x1.u = traw[kk * 4 + 1];
        x2.u = traw[kk * 4 + 2]; x3.u = traw[kk * 4 + 3];
        if (notlast) {
          const int nk = ((sub + 1) % 3) * 3 + kk;  // static
          ushort4 ti = tir[nk]; float4 twn = twr[nk];
          uint4 t0 = z4, t1 = z4, t2 = z4, t3 = z4;
          if (__any(twn.x != 0.f)) t0 = *(const uint4*)&xb[(size_t)ti.x * 256 + ncbase];
          if (__any(twn.y != 0.f)) t1 = *(const uint4*)&xb[(size_t)ti.y * 256 + ncbase];
          if (__any(twn.z != 0.f)) t2 = *(const uint4*)&xb[(size_t)ti.z * 256 + ncbase];
          if (__any(twn.w != 0.f)) t3 = *(const uint4*)&xb[(size_t)ti.w * 256 + ncbase];
          traw[kk * 4 + 0] = t0; traw[kk * 4 + 1] = t1;
          traw[kk * 4 + 2] = t2; traw[kk * 4 + 3] = t3;
        }
        float r[8];
#pragma unroll
        for (int j = 0; j < 8; ++j) r[j] = tw.x * bf2f((unsigned short)x0.s[j]);
        if (__any(tw.y != 0.f)) {
#pragma unroll
          for (int j = 0; j < 8; ++j) r[j] += tw.y * bf2f((unsigned short)x1.s[j]);
        }
        if (__any(tw.z != 0.f)) {
#pragma unroll
          for (int j = 0; j < 8; ++j) r[j] += tw.z * bf2f((unsigned short)x2.s[j]);
        }
        if (__any(tw.w != 0.f)) {
#pragma unroll
          for (int j = 0; j < 8; ++j) r[j] += tw.w * bf2f((unsigned short)x3.s[j]);
        }
        union { uint4 u; short8 s; } bu;
        bu.u = make_uint4(bf16h(r[0]) | (bf16h(r[1]) << 16), bf16h(r[2]) | (bf16h(r[3]) << 16),
                          bf16h(r[4]) | (bf16h(r[5]) << 16), bf16h(r[6]) | (bf16h(r[7]) << 16));
        const unsigned short* bk = buf + kk * 4096 + lane * 8;
#pragma unroll
        for (int ot = 0; ot < 8; ++ot) {
          short8 af = *(const short8*)&bk[ot * 512];
          acc[ot] = __builtin_amdgcn_mfma_f32_16x16x32_bf16(af, bu.s, acc[ot], 0, 0, 0);
        }
      }
      __syncthreads();  // drains glds(next) + all waves done reading buf
    }
  }

  // epilogue: BN+ReLU then R[slot][px] = sum_o v[o][slot]*yv, reduced over quads
  float* sv = (float*)sW;          // 128*17 vtab (stride 17) + bn
  float* sbn = sv + 2176;
  for (int i = t; i < 2048; i += 512) sv[(i >> 4) * 17 + (i & 15)] = vtab[i];
  if (t < 256) sbn[t] = bntab[t];
  __syncthreads();

  float rpart[16];
#pragma unroll
  for (int i = 0; i < 16; ++i) rpart[i] = 0.f;
#pragma unroll
  for (int ot = 0; ot < 8; ++ot)
#pragma unroll
    for (int r = 0; r < 4; ++r) {
      int o = ot * 16 + quad * 4 + r;
      float yv = fmaxf(acc[ot][r] * sbn[o] + sbn[128 + o], 0.f);
      const float* vp = &sv[o * 17];
#pragma unroll
      for (int tt = 0; tt < 16; ++tt) rpart[tt] += vp[tt] * yv;
    }
#pragma unroll
  for (int tt = 0; tt < 16; ++tt) {
    rpart[tt] += __shfl_xor(rpart[tt], 16, 64);
    rpart[tt] += __shfl_xor(rpart[tt], 32, 64);
  }
  // R planes: [b][slot][pixel] -> coalesced stores
#pragma unroll
  for (int j = 0; j < 4; ++j) {
    int slot = quad * 4 + j;
    R[(((size_t)(b * 16 + slot)) << 12) + row * 64 + px] = rpart[slot];
  }
}

// ---------------------------------------------------------------------------
// K3: upsample+1x1+sigmoid from R planes: 4 coalesced loads + sigmoid
// ---------------------------------------------------------------------------
__global__ __launch_bounds__(256) void k_upb(
    const float* __restrict__ R, float* __restrict__ out) {
  int b = blockIdx.x & 7, sub = blockIdx.x >> 3;
  int inner = sub * 256 + threadIdx.x;        // 0..16383
  int X = inner & 127, Y = inner >> 7;        // Y 0..127
  int i0, wu0, wu1, j0, wv0, wv1;
  if (Y & 1) { i0 = (Y - 1) >> 1; wu0 = 2; wu1 = 0; }
  else       { i0 = (Y - 2) / 2;  wu0 = 3; wu1 = 1; }
  if (X & 1) { j0 = (X - 1) >> 1; wv0 = 2; wv1 = 0; }
  else       { j0 = (X - 2) / 2;  wv0 = 3; wv1 = 1; }
  int i1 = i0 + 1, j1 = j0 + 1;
  float mi0 = ((unsigned)i0 < 64u) ? 1.f : 0.f;
  float mi1 = ((unsigned)i1 < 64u) ? 1.f : 0.f;
  float mj0 = ((unsigned)j0 < 64u) ? 1.f : 0.f;
  float mj1 = ((unsigned)j1 < 64u) ? 1.f : 0.f;
  int i0c = min(max(i0, 0), 63), i1c = min(max(i1, 0), 63);
  int j0c = min(max(j0, 0), 63), j1c = min(max(j1, 0), 63);
  const float* Rb = R + (((size_t)b) << 16);   // b*16*4096
  float s = mi0 * mj0 * Rb[((wu0 * 4 + wv0) << 12) + (i0c << 6) + j0c] +
            mi0 * mj1 * Rb[((wu0 * 4 + wv1) << 12) + (i0c << 6) + j1c] +
            mi1 * mj0 * Rb[((wu1 * 4 + wv0) << 12) + (i1c << 6) + j0c] +
            mi1 * mj1 * Rb[((wu1 * 4 + wv1) << 12) + (i1c << 6) + j1c];
  out[(b << 14) + inner] = 1.f / (1.f + __expf(-s));
}

// ---------------------------------------------------------------------------
extern "C" void kernel_launch(void* const* d_in, const int* in_sizes, int n_in,
                              void* d_out, int out_size, void* d_ws, size_t ws_size,
                              hipStream_t stream) {
  const float* x        = (const float*)d_in[0];
  const float* w_dcn    = (const float*)d_in[1];
  const float* b_dcn    = (const float*)d_in[2];
  const float* w_off    = (const float*)d_in[3];
  const float* b_off    = (const float*)d_in[4];
  const float* bn_gamma = (const float*)d_in[5];
  const float* bn_beta  = (const float*)d_in[6];
  const float* bn_mean  = (const float*)d_in[7];
  const float* bn_var   = (const float*)d_in[8];
  const float* w_up     = (const float*)d_in[9];
  const float* w_1x1    = (const float*)d_in[10];
  float* out = (float*)d_out;

  // ws layout in FLOAT units:
  float* ws = (float*)d_ws;
  unsigned short* xT     = (unsigned short*)ws;                    // 8388608 ush
  unsigned short* wt_dcn = (unsigned short*)(ws + 4194304);        //  294912 ush
  unsigned short* wt_off = (unsigned short*)(ws + 4341760);        //   73728 ush
  float* vtab            = ws + 4378624;                           //    2048 f
  float* bntab           = ws + 4380672;                           //     256 f
  unsigned int* offflags = (unsigned int*)(ws + 4380928);          //    1152 u32
  float* R               = ws + 4823296;                           //  524288 f

  k_pre<<<1152, 256, 0, stream>>>(x, w_dcn, w_off, b_dcn, bn_gamma, bn_beta,
                                  bn_mean, bn_var, w_up, w_1x1,
                                  xT, wt_dcn, wt_off, vtab, bntab, offflags);
  k_dcn<<<256, 512, 0, stream>>>(xT, wt_dcn, wt_off, b_off, vtab, bntab,
                                 offflags, R);
  k_upb<<<512, 256, 0, stream>>>(R, out);
}

// Round 7
// 147.556 us; speedup vs baseline: 1.3802x; 1.3802x over previous
//
#include <hip/hip_runtime.h>
#include <math.h>

typedef __attribute__((ext_vector_type(8))) short short8;
typedef __attribute__((ext_vector_type(4))) float floatx4;

__device__ __forceinline__ unsigned short bf16r(float f) {
  union { float f; unsigned int u; } v; v.f = f;
  unsigned int u = v.u;
  return (unsigned short)((u + 0x7fffu + ((u >> 16) & 1u)) >> 16);
}
// round-half-up pack (sampling path; 2 ops)
__device__ __forceinline__ unsigned int bf16h(float f) {
  union { float f; unsigned int u; } v; v.f = f;
  return (v.u + 0x8000u) >> 16;
}
__device__ __forceinline__ float bf2f(unsigned int u) {
  union { unsigned int u; float f; } v; v.u = u << 16; return v.f;
}
// async global->LDS DMA, 16B/lane; LDS dst = wave-uniform base + lane*16
__device__ __forceinline__ void glds16(const void* g, void* l) {
  __builtin_amdgcn_global_load_lds(
      (const __attribute__((address_space(1))) unsigned int*)g,
      (__attribute__((address_space(3))) unsigned int*)l, 16, 0, 0);
}

// ---------------------------------------------------------------------------
// K0 (MERGED prep + xT): weight prep (bf16, lane-linear MFMA-frag layouts),
// fused tables, w_off-nonzero flags, and the x->xT transpose.
// ---------------------------------------------------------------------------
__global__ __launch_bounds__(256) void k_pre(
    const float* __restrict__ x,
    const float* __restrict__ w_dcn, const float* __restrict__ w_off,
    const float* __restrict__ b_dcn,
    const float* __restrict__ bn_g, const float* __restrict__ bn_b,
    const float* __restrict__ bn_m, const float* __restrict__ bn_v,
    const float* __restrict__ w_up, const float* __restrict__ w1x1,
    unsigned short* __restrict__ xT,
    unsigned short* __restrict__ wt_dcn, unsigned short* __restrict__ wt_off,
    float* __restrict__ vtab, float* __restrict__ bntab,
    unsigned int* __restrict__ offflags) {
  __shared__ unsigned short sx[32 * 264];
  int e = blockIdx.x * 256 + threadIdx.x;
  if (e < 294912) {
    int s = e >> 12;            // s = cg*9 + k  (72 tiles of 4096 ush)
    int r = e & 4095;
    int ot = r >> 9;            // 8 output-tiles of 512 ush
    int lane = (r >> 3) & 63;   // wave lane this element feeds
    int j = e & 7;
    int l15 = lane & 15, quad = lane >> 4;
    int o = ot * 16 + l15;
    int k = s % 9, cg = s / 9;
    int c = cg * 32 + quad * 8 + j;
    wt_dcn[e] = bf16r(w_dcn[(o * 256 + c) * 9 + k]);
  }
  bool nz = false;
  if (e < 73728) {
    int cg = e / 9216;
    int r = e % 9216;
    int frag = r >> 9;          // 18 frags: (k,ot)
    int k = frag >> 1, ot = frag & 1;
    int lane = (r >> 3) & 63, j = e & 7;
    int l15 = lane & 15, quad = lane >> 4;
    int oc = ot * 16 + l15;
    int c = cg * 32 + quad * 8 + j;
    float wv = (oc < 27) ? w_off[(oc * 256 + c) * 9 + k] : 0.f;
    wt_off[e] = bf16r(wv);
    nz = (wv != 0.f);
  }
  unsigned long long ba = __ballot(nz);
  if (blockIdx.x < 288 && (threadIdx.x & 63) == 0)
    offflags[blockIdx.x * 4 + (threadIdx.x >> 6)] = (ba != 0ull) ? 1u : 0u;
  if (e < 2048) {
    int o = e >> 4;
    vtab[e] = w1x1[o] * w_up[e];
  }
  if (e < 128) {
    float g = bn_g[e] * rsqrtf(bn_v[e] + 1e-5f);
    bntab[e] = g;
    bntab[128 + e] = (b_dcn[e] - bn_m[e]) * g + bn_b[e];
  }
  if (blockIdx.x < 1024) {
    int b = blockIdx.x & 7, px0 = ((blockIdx.x >> 3) & 127) * 32;
    int t = threadIdx.x;
    int px = t & 31, cg = t >> 5;
    const float* xsrc = x + (((size_t)(b * 256 + cg * 32)) << 12) + px0 + px;
#pragma unroll
    for (int cc = 0; cc < 32; ++cc)
      sx[px * 264 + cg * 32 + cc] = bf16r(xsrc[(size_t)cc << 12]);
    __syncthreads();
#pragma unroll
    for (int j = 0; j < 4; ++j) {
      int unit = t + j * 256;
      int p = unit >> 5, chunk = unit & 31;
      uint4 v = *(const uint4*)&sx[p * 264 + chunk * 8];
      *(uint4*)&xT[((size_t)((b << 12) + px0 + p)) * 256 + chunk * 8] = v;
    }
  }
}

// ---------------------------------------------------------------------------
// K2 (FUSED): offset-conv + DCNv2 MFMA + BN/ReLU + fused (upsample x 1x1) -> R.
// R5 structure (proven: VGPR 88, no spill, k_dcn 77.8us) plus ONE change:
// FAST-PATH L2 WARMING -- coalesced keep-alive sweep of this block's 3 xT
// rows (row-1..row+1) right after the flag check.  R3/R4 showed the main
// loop runs at ~54us when the (b,row) xT neighborhood is already in the
// home-XCD L2 and ~78us when the main loop is the first toucher (R5).  The
// sweep's L2 fill overlaps prologue-B tap math + phase-0 staging.
// XCD-swizzled: batch b -> XCD b.
// ---------------------------------------------------------------------------
__global__ __launch_bounds__(256, 2) void k_dcn(
    const unsigned short* __restrict__ xT, const unsigned short* __restrict__ wt,
    const unsigned short* __restrict__ wtoff, const float* __restrict__ b_off,
    const float* __restrict__ vtab, const float* __restrict__ bntab,
    const unsigned int* __restrict__ offflags, float* __restrict__ R) {
  int b = blockIdx.x & 7, row = blockIdx.x >> 3;
  __shared__ unsigned short sW[2 * 12288];   // 49152 B; prologue-A: 2 x 9216-ush
  __shared__ ushort4 s_ti[576];              // 4608 B; first 3456 B = som (bf16)
  __shared__ float4 s_tw[576];               // 9216 B
  __shared__ unsigned int s_fl[4];
  int t = threadIdx.x, lane = t & 63, wvx = t >> 6;
  int l15 = lane & 15, quad = lane >> 4;
  int px = wvx * 16 + l15;                   // this thread's pixel column
  const unsigned short* xb = xT + (((size_t)b) << 12) * 256;
  const short8 zz = {0, 0, 0, 0, 0, 0, 0, 0};
  unsigned short* som = (unsigned short*)s_ti;   // 27*64 bf16 = 3456 B

  // ---- w_off-nonzero flag (grid-uniform) ----------------------------------
  {
    unsigned int a = 0;
    for (int i = t; i < 1152; i += 256) a |= offflags[i];
    a = __any(a != 0u) ? 1u : 0u;
    if (lane == 0) s_fl[wvx] = a;
  }
  __syncthreads();
  const bool offnz = (s_fl[0] | s_fl[1] | s_fl[2] | s_fl[3]) != 0u;

  if (!offnz) {
    // FAST-PATH warming: coalesced sweep of rows row-1..row+1 into home L2.
    // Keep-alive asm (rule #17) prevents DCE; values are never used.
    int wr0 = max(row - 1, 0), wr1 = min(row + 1, 63);
    for (int rr = wr0; rr <= wr1; ++rr) {
      const uint4* src = (const uint4*)(xb + ((size_t)(rr << 6)) * 256);
#pragma unroll
      for (int i = 0; i < 8; ++i) {
        uint4 v = src[t + (i << 8)];
        asm volatile("" :: "v"(v.x), "v"(v.y), "v"(v.z), "v"(v.w));
      }
    }
  }

  // ---- prologue-A (slow path only): offset conv for (b,row) ---------------
  if (offnz) {
    int pixk[9]; bool vkk[9];
#pragma unroll
    for (int k = 0; k < 9; ++k) {
      int yy = row + k / 3 - 1, xx = px + k % 3 - 1;
      vkk[k] = ((unsigned)yy < 64u) & ((unsigned)xx < 64u);
      pixk[k] = vkk[k] ? (yy * 64 + xx) : 0;
    }
    floatx4 oacc[2];
    oacc[0] = (floatx4){0.f, 0.f, 0.f, 0.f};
    oacc[1] = (floatx4){0.f, 0.f, 0.f, 0.f};

#pragma unroll
    for (int i = 0; i < 5; ++i) {
      int frag = wvx + i * 4;
      if (frag < 18)
        glds16(wtoff + (size_t)frag * 512 + lane * 8, &sW[frag * 512]);
    }
    __syncthreads();   // buf0 weights ready

    for (int cg = 0; cg < 8; ++cg) {
      unsigned short* buf = sW + (cg & 1) * 9216;
      int cb = cg * 32 + quad * 8;
      short8 bx[9];
#pragma unroll
      for (int k = 0; k < 9; ++k) {
        short8 v = *(const short8*)&xb[(size_t)pixk[k] * 256 + cb];
        bx[k] = vkk[k] ? v : zz;
      }
      if (cg < 7) {
        const unsigned short* wsrc = wtoff + (size_t)(cg + 1) * 9216;
        unsigned short* nbuf = sW + ((cg + 1) & 1) * 9216;
#pragma unroll
        for (int i = 0; i < 5; ++i) {
          int frag = wvx + i * 4;
          if (frag < 18)
            glds16(wsrc + (size_t)frag * 512 + lane * 8, &nbuf[frag * 512]);
        }
      }
#pragma unroll
      for (int k = 0; k < 9; ++k) {
        short8 a0 = *(const short8*)&buf[(k * 2 + 0) * 512 + lane * 8];
        short8 a1 = *(const short8*)&buf[(k * 2 + 1) * 512 + lane * 8];
        oacc[0] = __builtin_amdgcn_mfma_f32_16x16x32_bf16(a0, bx[k], oacc[0], 0, 0, 0);
        oacc[1] = __builtin_amdgcn_mfma_f32_16x16x32_bf16(a1, bx[k], oacc[1], 0, 0, 0);
      }
      __syncthreads();
    }
#pragma unroll
    for (int ot = 0; ot < 2; ++ot)
#pragma unroll
      for (int r = 0; r < 4; ++r) {
        int o = ot * 16 + quad * 4 + r;
        if (o < 27) som[o * 64 + px] = bf16r(oacc[ot][r] + b_off[o]);
      }
    __syncthreads();   // som complete
  }

  // ---- prologue-B: taps = 4 clamped pixel indices + 4 weights per (k,px) ---
  {
    float to1[3], to2[3], tmv[3];
    if (offnz) {
#pragma unroll
      for (int ii = 0; ii < 3; ++ii) {
        int i = t + ii * 256;
        if (i < 576) {
          int k = i >> 6, p = i & 63;
          to1[ii] = bf2f(som[k * 64 + p]);
          to2[ii] = bf2f(som[(9 + k) * 64 + p]);
          tmv[ii] = bf2f(som[(18 + k) * 64 + p]);
        }
      }
      __syncthreads();   // all som reads done before s_ti overwrites
    } else {
#pragma unroll
      for (int ii = 0; ii < 3; ++ii) {
        int i = t + ii * 256;
        if (i < 576) {
          int k = i >> 6;
          to1[ii] = bf2f(bf16r(b_off[k]));        // == bf16r(0 + b_off)
          to2[ii] = bf2f(bf16r(b_off[9 + k]));
          tmv[ii] = bf2f(bf16r(b_off[18 + k]));
        }
      }
    }
#pragma unroll
    for (int ii = 0; ii < 3; ++ii) {
      int i = t + ii * 256;
      if (i < 576) {
        int k = i >> 6, p = i & 63;
        float m = 1.f / (1.f + __expf(-tmv[ii]));
        float py = (float)(row + k / 3 - 1) + to1[ii];
        float pxf = (float)(p + (k % 3) - 1) + to2[ii];
        float fy = floorf(py), fx = floorf(pxf);
        int iy = (int)fy, ix = (int)fx;
        float wy1 = py - fy, wy0 = 1.f - wy1;
        float wx1 = pxf - fx, wx0 = 1.f - wx1;
        bool y0ok = (iy >= 0) & (iy < 64), y1ok = (iy >= -1) & (iy < 63);
        bool x0ok = (ix >= 0) & (ix < 64), x1ok = (ix >= -1) & (ix < 63);
        int iy0 = min(max(iy, 0), 63), iy1 = min(max(iy + 1, 0), 63);
        int ix0 = min(max(ix, 0), 63), ix1 = min(max(ix + 1, 0), 63);
        s_ti[i] = make_ushort4((unsigned short)(iy0 * 64 + ix0), (unsigned short)(iy0 * 64 + ix1),
                               (unsigned short)(iy1 * 64 + ix0), (unsigned short)(iy1 * 64 + ix1));
        float4 w;
        w.x = (y0ok && x0ok) ? m * wy0 * wx0 : 0.f;
        w.y = (y0ok && x1ok) ? m * wy0 * wx1 : 0.f;
        w.z = (y1ok && x0ok) ? m * wy1 * wx0 : 0.f;
        w.w = (y1ok && x1ok) ? m * wy1 * wx1 : 0.f;
        s_tw[i] = w;
      }
    }
  }
  __syncthreads();   // s_ti/s_tw ready (read-only hereafter)

  const uint4 z4 = make_uint4(0u, 0u, 0u, 0u);

  floatx4 acc[8];
#pragma unroll
  for (int i = 0; i < 8; ++i) acc[i] = (floatx4){0.f, 0.f, 0.f, 0.f};

  // tap raw data for current phase (prefetched one phase ahead)
  uint4 traw[12];   // [kk][tap]
  {
    int cbase = quad * 8;                       // phase 0: cg=0
#pragma unroll
    for (int kk = 0; kk < 3; ++kk) {
      ushort4 ti = s_ti[(kk << 6) + px];        // phase 0: k = kk
      float4 twn = s_tw[(kk << 6) + px];
      uint4 t0 = z4, t1 = z4, t2 = z4, t3 = z4;
      if (__any(twn.x != 0.f)) t0 = *(const uint4*)&xb[(size_t)ti.x * 256 + cbase];
      if (__any(twn.y != 0.f)) t1 = *(const uint4*)&xb[(size_t)ti.y * 256 + cbase];
      if (__any(twn.z != 0.f)) t2 = *(const uint4*)&xb[(size_t)ti.z * 256 + cbase];
      if (__any(twn.w != 0.f)) t3 = *(const uint4*)&xb[(size_t)ti.w * 256 + cbase];
      traw[kk * 4 + 0] = t0; traw[kk * 4 + 1] = t1;
      traw[kk * 4 + 2] = t2; traw[kk * 4 + 3] = t3;
    }
  }
  {  // glds W(phase 0) -> buf 0
    const unsigned short* wsrc = wt;
#pragma unroll
    for (int i = 0; i < 6; ++i) {
      int blk = wvx * 6 + i;
      glds16(wsrc + (size_t)blk * 512 + lane * 8, &sW[blk * 512]);
    }
  }
  __syncthreads();   // buf0 complete (vmcnt drain) + taps in regs

  int lofs = lane * 8;   // lane-linear A-frag offset (ushorts)

  for (int phase = 0; phase < 24; ++phase) {
    unsigned short* buf = sW + (phase & 1) * 12288;
    unsigned short* nbuf = sW + ((phase + 1) & 1) * 12288;
    // issue next W DMA first (overlaps everything below)
    if (phase < 23) {
      const unsigned short* wsrc = wt + (size_t)(phase + 1) * 12288;
#pragma unroll
      for (int i = 0; i < 6; ++i) {
        int blk = wvx * 6 + i;
        glds16(wsrc + (size_t)blk * 512 + lane * 8, &nbuf[blk * 512]);
      }
    }
    int nphase = phase + 1;
    int ncbase = (nphase / 3) * 32 + quad * 8;

#pragma unroll
    for (int kk = 0; kk < 3; ++kk) {
      int k = (phase % 3) * 3 + kk;
      // current-phase tap weights + raw data (prefetched)
      float4 tw = s_tw[(k << 6) + px];
      union { uint4 u; short8 s; } x0, x1, x2, x3;
      x0.u = traw[kk * 4 + 0]; x1.u = traw[kk * 4 + 1];
      x2.u = traw[kk * 4 + 2]; x3.u = traw[kk * 4 + 3];
      // prefetch taps for next phase into same slots (consumed above),
      // skipping gathers whose weights are zero across the wave
      if (phase < 23) {
        int nk = (nphase % 3) * 3 + kk;
        ushort4 ti = s_ti[(nk << 6) + px];
        float4 twn = s_tw[(nk << 6) + px];
        uint4 t0 = z4, t1 = z4, t2 = z4, t3 = z4;
        if (__any(twn.x != 0.f)) t0 = *(const uint4*)&xb[(size_t)ti.x * 256 + ncbase];
        if (__any(twn.y != 0.f)) t1 = *(const uint4*)&xb[(size_t)ti.y * 256 + ncbase];
        if (__any(twn.z != 0.f)) t2 = *(const uint4*)&xb[(size_t)ti.z * 256 + ncbase];
        if (__any(twn.w != 0.f)) t3 = *(const uint4*)&xb[(size_t)ti.w * 256 + ncbase];
        traw[kk * 4 + 0] = t0; traw[kk * 4 + 1] = t1;
        traw[kk * 4 + 2] = t2; traw[kk * 4 + 3] = t3;
      }
      // sampling: tap0 always; taps 1-3 skipped when wave-uniformly zero
      float r[8];
#pragma unroll
      for (int j = 0; j < 8; ++j) r[j] = tw.x * bf2f((unsigned short)x0.s[j]);
      if (__any(tw.y != 0.f)) {
#pragma unroll
        for (int j = 0; j < 8; ++j) r[j] += tw.y * bf2f((unsigned short)x1.s[j]);
      }
      if (__any(tw.z != 0.f)) {
#pragma unroll
        for (int j = 0; j < 8; ++j) r[j] += tw.z * bf2f((unsigned short)x2.s[j]);
      }
      if (__any(tw.w != 0.f)) {
#pragma unroll
        for (int j = 0; j < 8; ++j) r[j] += tw.w * bf2f((unsigned short)x3.s[j]);
      }
      union { uint4 u; short8 s; } bu;
      bu.u = make_uint4(bf16h(r[0]) | (bf16h(r[1]) << 16), bf16h(r[2]) | (bf16h(r[3]) << 16),
                        bf16h(r[4]) | (bf16h(r[5]) << 16), bf16h(r[6]) | (bf16h(r[7]) << 16));
      // MFMA for this kk; lane-linear A-frag reads (conflict-free)
      const unsigned short* bk = buf + kk * 4096 + lofs;
#pragma unroll
      for (int ot = 0; ot < 8; ++ot) {
        short8 af = *(const short8*)&bk[ot * 512];
        acc[ot] = __builtin_amdgcn_mfma_f32_16x16x32_bf16(af, bu.s, acc[ot], 0, 0, 0);
      }
    }
    __syncthreads();  // drains glds(next) + all waves done reading buf
  }

  // epilogue: BN+ReLU then R[slot][px] = sum_o v[o][slot]*yv, reduced over quads
  float* sv = (float*)sW;          // 128*17 vtab (stride 17: conflict-free) + bn
  float* sbn = sv + 2176;
  for (int i = t; i < 2048; i += 256) sv[(i >> 4) * 17 + (i & 15)] = vtab[i];
  if (t < 256) sbn[t] = bntab[t];
  __syncthreads();

  float rpart[16];
#pragma unroll
  for (int i = 0; i < 16; ++i) rpart[i] = 0.f;
#pragma unroll
  for (int ot = 0; ot < 8; ++ot)
#pragma unroll
    for (int r = 0; r < 4; ++r) {
      int o = ot * 16 + quad * 4 + r;
      float yv = fmaxf(acc[ot][r] * sbn[o] + sbn[128 + o], 0.f);
      const float* vp = &sv[o * 17];
#pragma unroll
      for (int tt = 0; tt < 16; ++tt) rpart[tt] += vp[tt] * yv;
    }
#pragma unroll
  for (int tt = 0; tt < 16; ++tt) {
    rpart[tt] += __shfl_xor(rpart[tt], 16, 64);
    rpart[tt] += __shfl_xor(rpart[tt], 32, 64);
  }
  // R planes: [b][slot][pixel] -> 4-line coalesced stores
#pragma unroll
  for (int j = 0; j < 4; ++j) {
    int slot = quad * 4 + j;
    R[(((size_t)(b * 16 + slot)) << 12) + row * 64 + px] = rpart[slot];
  }
}

// ---------------------------------------------------------------------------
// K3: upsample+1x1+sigmoid from R planes: 4 coalesced loads + sigmoid
// ---------------------------------------------------------------------------
__global__ __launch_bounds__(256) void k_upb(
    const float* __restrict__ R, float* __restrict__ out) {
  int b = blockIdx.x & 7, sub = blockIdx.x >> 3;
  int inner = sub * 256 + threadIdx.x;        // 0..16383
  int X = inner & 127, Y = inner >> 7;        // Y 0..127
  int i0, wu0, wu1, j0, wv0, wv1;
  if (Y & 1) { i0 = (Y - 1) >> 1; wu0 = 2; wu1 = 0; }
  else       { i0 = (Y - 2) / 2;  wu0 = 3; wu1 = 1; }
  if (X & 1) { j0 = (X - 1) >> 1; wv0 = 2; wv1 = 0; }
  else       { j0 = (X - 2) / 2;  wv0 = 3; wv1 = 1; }
  int i1 = i0 + 1, j1 = j0 + 1;
  float mi0 = ((unsigned)i0 < 64u) ? 1.f : 0.f;
  float mi1 = ((unsigned)i1 < 64u) ? 1.f : 0.f;
  float mj0 = ((unsigned)j0 < 64u) ? 1.f : 0.f;
  float mj1 = ((unsigned)j1 < 64u) ? 1.f : 0.f;
  int i0c = min(max(i0, 0), 63), i1c = min(max(i1, 0), 63);
  int j0c = min(max(j0, 0), 63), j1c = min(max(j1, 0), 63);
  const float* Rb = R + (((size_t)b) << 16);   // b*16*4096
  float s = mi0 * mj0 * Rb[((wu0 * 4 + wv0) << 12) + (i0c << 6) + j0c] +
            mi0 * mj1 * Rb[((wu0 * 4 + wv1) << 12) + (i0c << 6) + j1c] +
            mi1 * mj0 * Rb[((wu1 * 4 + wv0) << 12) + (i1c << 6) + j0c] +
            mi1 * mj1 * Rb[((wu1 * 4 + wv1) << 12) + (i1c << 6) + j1c];
  out[(b << 14) + inner] = 1.f / (1.f + __expf(-s));
}

// ---------------------------------------------------------------------------
extern "C" void kernel_launch(void* const* d_in, const int* in_sizes, int n_in,
                              void* d_out, int out_size, void* d_ws, size_t ws_size,
                              hipStream_t stream) {
  const float* x        = (const float*)d_in[0];
  const float* w_dcn    = (const float*)d_in[1];
  const float* b_dcn    = (const float*)d_in[2];
  const float* w_off    = (const float*)d_in[3];
  const float* b_off    = (const float*)d_in[4];
  const float* bn_gamma = (const float*)d_in[5];
  const float* bn_beta  = (const float*)d_in[6];
  const float* bn_mean  = (const float*)d_in[7];
  const float* bn_var   = (const float*)d_in[8];
  const float* w_up     = (const float*)d_in[9];
  const float* w_1x1    = (const float*)d_in[10];
  float* out = (float*)d_out;

  // ws layout in FLOAT units:
  float* ws = (float*)d_ws;
  unsigned short* xT     = (unsigned short*)ws;                    // 8388608 ush
  unsigned short* wt_dcn = (unsigned short*)(ws + 4194304);        //  294912 ush
  unsigned short* wt_off = (unsigned short*)(ws + 4341760);        //   73728 ush
  float* vtab            = ws + 4378624;                           //    2048 f
  float* bntab           = ws + 4380672;                           //     256 f
  unsigned int* offflags = (unsigned int*)(ws + 4380928);          //    1152 u32
  float* R               = ws + 4823296;                           //  524288 f

  k_pre<<<1152, 256, 0, stream>>>(x, w_dcn, w_off, b_dcn, bn_gamma, bn_beta,
                                  bn_mean, bn_var, w_up, w_1x1,
                                  xT, wt_dcn, wt_off, vtab, bntab, offflags);
  k_dcn<<<512, 256, 0, stream>>>(xT, wt_dcn, wt_off, b_off, vtab, bntab,
                                 offflags, R);
  k_upb<<<512, 256, 0, stream>>>(R, out);
}

// Round 8
// 143.927 us; speedup vs baseline: 1.4150x; 1.0252x over previous
//
#include <hip/hip_runtime.h>
#include <math.h>

typedef __attribute__((ext_vector_type(8))) short short8;
typedef __attribute__((ext_vector_type(4))) float floatx4;

__device__ __forceinline__ unsigned short bf16r(float f) {
  union { float f; unsigned int u; } v; v.f = f;
  unsigned int u = v.u;
  return (unsigned short)((u + 0x7fffu + ((u >> 16) & 1u)) >> 16);
}
// round-half-up pack (sampling path; 2 ops)
__device__ __forceinline__ unsigned int bf16h(float f) {
  union { float f; unsigned int u; } v; v.f = f;
  return (v.u + 0x8000u) >> 16;
}
__device__ __forceinline__ float bf2f(unsigned int u) {
  union { unsigned int u; float f; } v; v.u = u << 16; return v.f;
}
// async global->LDS DMA, 16B/lane; LDS dst = wave-uniform base + lane*16
__device__ __forceinline__ void glds16(const void* g, void* l) {
  __builtin_amdgcn_global_load_lds(
      (const __attribute__((address_space(1))) unsigned int*)g,
      (__attribute__((address_space(3))) unsigned int*)l, 16, 0, 0);
}

// ---------------------------------------------------------------------------
// K0 (MERGED prep + xT): weight prep (bf16, lane-linear MFMA-frag layouts),
// fused tables, w_off-nonzero flags, and the x->xT transpose.
// ---------------------------------------------------------------------------
__global__ __launch_bounds__(256) void k_pre(
    const float* __restrict__ x,
    const float* __restrict__ w_dcn, const float* __restrict__ w_off,
    const float* __restrict__ b_dcn,
    const float* __restrict__ bn_g, const float* __restrict__ bn_b,
    const float* __restrict__ bn_m, const float* __restrict__ bn_v,
    const float* __restrict__ w_up, const float* __restrict__ w1x1,
    unsigned short* __restrict__ xT,
    unsigned short* __restrict__ wt_dcn, unsigned short* __restrict__ wt_off,
    float* __restrict__ vtab, float* __restrict__ bntab,
    unsigned int* __restrict__ offflags) {
  __shared__ unsigned short sx[32 * 264];
  int e = blockIdx.x * 256 + threadIdx.x;
  if (e < 294912) {
    int s = e >> 12;            // s = cg*9 + k  (72 tiles of 4096 ush)
    int r = e & 4095;
    int ot = r >> 9;            // 8 output-tiles of 512 ush
    int lane = (r >> 3) & 63;   // wave lane this element feeds
    int j = e & 7;
    int l15 = lane & 15, quad = lane >> 4;
    int o = ot * 16 + l15;
    int k = s % 9, cg = s / 9;
    int c = cg * 32 + quad * 8 + j;
    wt_dcn[e] = bf16r(w_dcn[(o * 256 + c) * 9 + k]);
  }
  bool nz = false;
  if (e < 73728) {
    int cg = e / 9216;
    int r = e % 9216;
    int frag = r >> 9;          // 18 frags: (k,ot)
    int k = frag >> 1, ot = frag & 1;
    int lane = (r >> 3) & 63, j = e & 7;
    int l15 = lane & 15, quad = lane >> 4;
    int oc = ot * 16 + l15;
    int c = cg * 32 + quad * 8 + j;
    float wv = (oc < 27) ? w_off[(oc * 256 + c) * 9 + k] : 0.f;
    wt_off[e] = bf16r(wv);
    nz = (wv != 0.f);
  }
  unsigned long long ba = __ballot(nz);
  if (blockIdx.x < 288 && (threadIdx.x & 63) == 0)
    offflags[blockIdx.x * 4 + (threadIdx.x >> 6)] = (ba != 0ull) ? 1u : 0u;
  if (e < 2048) {
    int o = e >> 4;
    vtab[e] = w1x1[o] * w_up[e];
  }
  if (e < 128) {
    float g = bn_g[e] * rsqrtf(bn_v[e] + 1e-5f);
    bntab[e] = g;
    bntab[128 + e] = (b_dcn[e] - bn_m[e]) * g + bn_b[e];
  }
  if (blockIdx.x < 1024) {
    int b = blockIdx.x & 7, px0 = ((blockIdx.x >> 3) & 127) * 32;
    int t = threadIdx.x;
    int px = t & 31, cg = t >> 5;
    const float* xsrc = x + (((size_t)(b * 256 + cg * 32)) << 12) + px0 + px;
#pragma unroll
    for (int cc = 0; cc < 32; ++cc)
      sx[px * 264 + cg * 32 + cc] = bf16r(xsrc[(size_t)cc << 12]);
    __syncthreads();
#pragma unroll
    for (int j = 0; j < 4; ++j) {
      int unit = t + j * 256;
      int p = unit >> 5, chunk = unit & 31;
      uint4 v = *(const uint4*)&sx[p * 264 + chunk * 8];
      *(uint4*)&xT[((size_t)((b << 12) + px0 + p)) * 256 + chunk * 8] = v;
    }
  }
}

// ---------------------------------------------------------------------------
// K2u (ULTRA): runs iff w_off == 0 AND b_off == 0 (checked on device; the
// setup distribution).  Then om = 0 exactly -> offsets 0, mask = sigmoid(0)
// = 0.5 exactly, sampling positions integral with uniform tap weight 0.5.
// B = 0.5*x and MFMA(W, 0.5x) == 0.5*MFMA(W, x) bitwise (pow2 scaling
// commutes with f32 rounding), so the 0.5 folds into the epilogue BN scale
// (0.5*g exact).  The ENTIRE sampling stage (tap tables, bf2f/FMA/bf16h
// repack) vanishes: main loop = load-select-MFMA, bit-identical output.
// No s_ti/s_tw -> LDS 49.2 KB -> 3 blocks/CU (12 waves, +50% TLP).
// XCD-swizzled: batch b -> XCD b.  Warming sweep kept (proven R7).
// ---------------------------------------------------------------------------
__global__ __launch_bounds__(256, 3) void k_dcnu(
    const unsigned short* __restrict__ xT, const unsigned short* __restrict__ wt,
    const float* __restrict__ b_off, const float* __restrict__ vtab,
    const float* __restrict__ bntab, const unsigned int* __restrict__ offflags,
    float* __restrict__ R) {
  int b = blockIdx.x & 7, row = blockIdx.x >> 3;
  __shared__ unsigned short sW[2 * 12288];   // 49152 B
  __shared__ unsigned int s_fl[8];
  int t = threadIdx.x, lane = t & 63, wvx = t >> 6;
  int l15 = lane & 15, quad = lane >> 4;
  int px = wvx * 16 + l15;
  const unsigned short* xb = xT + (((size_t)b) << 12) * 256;
  const short8 zz = {0, 0, 0, 0, 0, 0, 0, 0};

  // ---- flags: ultra iff all w_off == 0 AND all b_off == 0 -----------------
  {
    unsigned int a = 0;
    for (int i = t; i < 1152; i += 256) a |= offflags[i];
    unsigned int bo = (lane < 27 && b_off[lane] != 0.f) ? 1u : 0u;
    a = __any(a != 0u) ? 1u : 0u;
    bo = __any(bo != 0u) ? 1u : 0u;
    if (lane == 0) { s_fl[wvx] = a; s_fl[4 + wvx] = bo; }
  }
  __syncthreads();
  if ((s_fl[0] | s_fl[1] | s_fl[2] | s_fl[3] |
       s_fl[4] | s_fl[5] | s_fl[6] | s_fl[7]) != 0u)
    return;   // not ultra: k_dcng handles this case

  // warming sweep: rows row-1..row+1 into home-XCD L2 (keep-alive, rule #17)
  {
    int wr0 = max(row - 1, 0), wr1 = min(row + 1, 63);
    for (int rr = wr0; rr <= wr1; ++rr) {
      const uint4* src = (const uint4*)(xb + ((size_t)(rr << 6)) * 256);
#pragma unroll
      for (int i = 0; i < 8; ++i) {
        uint4 v = src[t + (i << 8)];
        asm volatile("" :: "v"(v.x), "v"(v.y), "v"(v.z), "v"(v.w));
      }
    }
  }

  // base conv taps (integral, offset 0): standard 3x3 pattern + validity
  int pixk[9]; bool vkk[9];
#pragma unroll
  for (int k = 0; k < 9; ++k) {
    int yy = row + k / 3 - 1, xx = px + k % 3 - 1;
    vkk[k] = ((unsigned)yy < 64u) & ((unsigned)xx < 64u);
    pixk[k] = vkk[k] ? (yy * 64 + xx) : 0;
  }

  floatx4 acc[8];
#pragma unroll
  for (int i = 0; i < 8; ++i) acc[i] = (floatx4){0.f, 0.f, 0.f, 0.f};

  // phase-0 B prefetch (cg=0, k=kk)
  uint4 traw[3];
  {
    int cbase = quad * 8;
#pragma unroll
    for (int kk = 0; kk < 3; ++kk)
      traw[kk] = *(const uint4*)&xb[(size_t)pixk[kk] * 256 + cbase];
  }
  {  // glds W(phase 0) -> buf 0
#pragma unroll
    for (int i = 0; i < 6; ++i) {
      int blk = wvx * 6 + i;
      glds16(wt + (size_t)blk * 512 + lane * 8, &sW[blk * 512]);
    }
  }
  __syncthreads();

  for (int phase = 0; phase < 24; ++phase) {
    unsigned short* buf = sW + (phase & 1) * 12288;
    unsigned short* nbuf = sW + ((phase + 1) & 1) * 12288;
    if (phase < 23) {
      const unsigned short* wsrc = wt + (size_t)(phase + 1) * 12288;
#pragma unroll
      for (int i = 0; i < 6; ++i) {
        int blk = wvx * 6 + i;
        glds16(wsrc + (size_t)blk * 512 + lane * 8, &nbuf[blk * 512]);
      }
    }
    int nphase = phase + 1;
    int ncbase = (nphase / 3) * 32 + quad * 8;

#pragma unroll
    for (int kk = 0; kk < 3; ++kk) {
      int k = (phase % 3) * 3 + kk;
      union { uint4 u; short8 s; } bx; bx.u = traw[kk];
      short8 bs = vkk[k] ? bx.s : zz;       // boundary zeroing = tap validity
      if (phase < 23) {                     // prefetch next phase's B
        int nk = (nphase % 3) * 3 + kk;
        traw[kk] = *(const uint4*)&xb[(size_t)pixk[nk] * 256 + ncbase];
      }
      const unsigned short* bk = buf + kk * 4096 + lane * 8;
#pragma unroll
      for (int ot = 0; ot < 8; ++ot) {
        short8 af = *(const short8*)&bk[ot * 512];
        acc[ot] = __builtin_amdgcn_mfma_f32_16x16x32_bf16(af, bs, acc[ot], 0, 0, 0);
      }
    }
    __syncthreads();
  }

  // epilogue: BN+ReLU with the 0.5 mask folded into the scale (exact)
  float* sv = (float*)sW;
  float* sbn = sv + 2176;
  for (int i = t; i < 2048; i += 256) sv[(i >> 4) * 17 + (i & 15)] = vtab[i];
  if (t < 256) sbn[t] = bntab[t];
  __syncthreads();

  float rpart[16];
#pragma unroll
  for (int i = 0; i < 16; ++i) rpart[i] = 0.f;
#pragma unroll
  for (int ot = 0; ot < 8; ++ot)
#pragma unroll
    for (int r = 0; r < 4; ++r) {
      int o = ot * 16 + quad * 4 + r;
      float yv = fmaxf(acc[ot][r] * (0.5f * sbn[o]) + sbn[128 + o], 0.f);
      const float* vp = &sv[o * 17];
#pragma unroll
      for (int tt = 0; tt < 16; ++tt) rpart[tt] += vp[tt] * yv;
    }
#pragma unroll
  for (int tt = 0; tt < 16; ++tt) {
    rpart[tt] += __shfl_xor(rpart[tt], 16, 64);
    rpart[tt] += __shfl_xor(rpart[tt], 32, 64);
  }
#pragma unroll
  for (int j = 0; j < 4; ++j) {
    int slot = quad * 4 + j;
    R[(((size_t)(b * 16 + slot)) << 12) + row * 64 + px] = rpart[slot];
  }
}

// ---------------------------------------------------------------------------
// K2g (GENERAL, R7 structure): handles w_off != 0 (full offset conv) or
// b_off != 0 (uniform-offset taps).  Early-returns when the ultra kernel
// is responsible.
// ---------------------------------------------------------------------------
__global__ __launch_bounds__(256, 2) void k_dcng(
    const unsigned short* __restrict__ xT, const unsigned short* __restrict__ wt,
    const unsigned short* __restrict__ wtoff, const float* __restrict__ b_off,
    const float* __restrict__ vtab, const float* __restrict__ bntab,
    const unsigned int* __restrict__ offflags, float* __restrict__ R) {
  int b = blockIdx.x & 7, row = blockIdx.x >> 3;
  __shared__ unsigned short sW[2 * 12288];   // 49152 B; prologue-A: 2 x 9216-ush
  __shared__ ushort4 s_ti[576];              // 4608 B; first 3456 B = som (bf16)
  __shared__ float4 s_tw[576];               // 9216 B
  __shared__ unsigned int s_fl[8];
  int t = threadIdx.x, lane = t & 63, wvx = t >> 6;
  int l15 = lane & 15, quad = lane >> 4;
  int px = wvx * 16 + l15;
  const unsigned short* xb = xT + (((size_t)b) << 12) * 256;
  const short8 zz = {0, 0, 0, 0, 0, 0, 0, 0};
  unsigned short* som = (unsigned short*)s_ti;   // 27*64 bf16 = 3456 B

  // ---- flags --------------------------------------------------------------
  {
    unsigned int a = 0;
    for (int i = t; i < 1152; i += 256) a |= offflags[i];
    unsigned int bo = (lane < 27 && b_off[lane] != 0.f) ? 1u : 0u;
    a = __any(a != 0u) ? 1u : 0u;
    bo = __any(bo != 0u) ? 1u : 0u;
    if (lane == 0) { s_fl[wvx] = a; s_fl[4 + wvx] = bo; }
  }
  __syncthreads();
  const bool offnz = (s_fl[0] | s_fl[1] | s_fl[2] | s_fl[3]) != 0u;
  const bool bofnz = (s_fl[4] | s_fl[5] | s_fl[6] | s_fl[7]) != 0u;
  if (!offnz && !bofnz) return;   // ultra: k_dcnu handles

  if (!offnz) {
    // warming sweep (b_off-only fast path)
    int wr0 = max(row - 1, 0), wr1 = min(row + 1, 63);
    for (int rr = wr0; rr <= wr1; ++rr) {
      const uint4* src = (const uint4*)(xb + ((size_t)(rr << 6)) * 256);
#pragma unroll
      for (int i = 0; i < 8; ++i) {
        uint4 v = src[t + (i << 8)];
        asm volatile("" :: "v"(v.x), "v"(v.y), "v"(v.z), "v"(v.w));
      }
    }
  }

  // ---- prologue-A (slow path only): offset conv for (b,row) ---------------
  if (offnz) {
    int pixk[9]; bool vkk[9];
#pragma unroll
    for (int k = 0; k < 9; ++k) {
      int yy = row + k / 3 - 1, xx = px + k % 3 - 1;
      vkk[k] = ((unsigned)yy < 64u) & ((unsigned)xx < 64u);
      pixk[k] = vkk[k] ? (yy * 64 + xx) : 0;
    }
    floatx4 oacc[2];
    oacc[0] = (floatx4){0.f, 0.f, 0.f, 0.f};
    oacc[1] = (floatx4){0.f, 0.f, 0.f, 0.f};

#pragma unroll
    for (int i = 0; i < 5; ++i) {
      int frag = wvx + i * 4;
      if (frag < 18)
        glds16(wtoff + (size_t)frag * 512 + lane * 8, &sW[frag * 512]);
    }
    __syncthreads();   // buf0 weights ready

    for (int cg = 0; cg < 8; ++cg) {
      unsigned short* buf = sW + (cg & 1) * 9216;
      int cb = cg * 32 + quad * 8;
      short8 bx[9];
#pragma unroll
      for (int k = 0; k < 9; ++k) {
        short8 v = *(const short8*)&xb[(size_t)pixk[k] * 256 + cb];
        bx[k] = vkk[k] ? v : zz;
      }
      if (cg < 7) {
        const unsigned short* wsrc = wtoff + (size_t)(cg + 1) * 9216;
        unsigned short* nbuf = sW + ((cg + 1) & 1) * 9216;
#pragma unroll
        for (int i = 0; i < 5; ++i) {
          int frag = wvx + i * 4;
          if (frag < 18)
            glds16(wsrc + (size_t)frag * 512 + lane * 8, &nbuf[frag * 512]);
        }
      }
#pragma unroll
      for (int k = 0; k < 9; ++k) {
        short8 a0 = *(const short8*)&buf[(k * 2 + 0) * 512 + lane * 8];
        short8 a1 = *(const short8*)&buf[(k * 2 + 1) * 512 + lane * 8];
        oacc[0] = __builtin_amdgcn_mfma_f32_16x16x32_bf16(a0, bx[k], oacc[0], 0, 0, 0);
        oacc[1] = __builtin_amdgcn_mfma_f32_16x16x32_bf16(a1, bx[k], oacc[1], 0, 0, 0);
      }
      __syncthreads();
    }
#pragma unroll
    for (int ot = 0; ot < 2; ++ot)
#pragma unroll
      for (int r = 0; r < 4; ++r) {
        int o = ot * 16 + quad * 4 + r;
        if (o < 27) som[o * 64 + px] = bf16r(oacc[ot][r] + b_off[o]);
      }
    __syncthreads();   // som complete
  }

  // ---- prologue-B: taps = 4 clamped pixel indices + 4 weights per (k,px) ---
  {
    float to1[3], to2[3], tmv[3];
    if (offnz) {
#pragma unroll
      for (int ii = 0; ii < 3; ++ii) {
        int i = t + ii * 256;
        if (i < 576) {
          int k = i >> 6, p = i & 63;
          to1[ii] = bf2f(som[k * 64 + p]);
          to2[ii] = bf2f(som[(9 + k) * 64 + p]);
          tmv[ii] = bf2f(som[(18 + k) * 64 + p]);
        }
      }
      __syncthreads();   // all som reads done before s_ti overwrites
    } else {
#pragma unroll
      for (int ii = 0; ii < 3; ++ii) {
        int i = t + ii * 256;
        if (i < 576) {
          int k = i >> 6;
          to1[ii] = bf2f(bf16r(b_off[k]));        // == bf16r(0 + b_off)
          to2[ii] = bf2f(bf16r(b_off[9 + k]));
          tmv[ii] = bf2f(bf16r(b_off[18 + k]));
        }
      }
    }
#pragma unroll
    for (int ii = 0; ii < 3; ++ii) {
      int i = t + ii * 256;
      if (i < 576) {
        int k = i >> 6, p = i & 63;
        float m = 1.f / (1.f + __expf(-tmv[ii]));
        float py = (float)(row + k / 3 - 1) + to1[ii];
        float pxf = (float)(p + (k % 3) - 1) + to2[ii];
        float fy = floorf(py), fx = floorf(pxf);
        int iy = (int)fy, ix = (int)fx;
        float wy1 = py - fy, wy0 = 1.f - wy1;
        float wx1 = pxf - fx, wx0 = 1.f - wx1;
        bool y0ok = (iy >= 0) & (iy < 64), y1ok = (iy >= -1) & (iy < 63);
        bool x0ok = (ix >= 0) & (ix < 64), x1ok = (ix >= -1) & (ix < 63);
        int iy0 = min(max(iy, 0), 63), iy1 = min(max(iy + 1, 0), 63);
        int ix0 = min(max(ix, 0), 63), ix1 = min(max(ix + 1, 0), 63);
        s_ti[i] = make_ushort4((unsigned short)(iy0 * 64 + ix0), (unsigned short)(iy0 * 64 + ix1),
                               (unsigned short)(iy1 * 64 + ix0), (unsigned short)(iy1 * 64 + ix1));
        float4 w;
        w.x = (y0ok && x0ok) ? m * wy0 * wx0 : 0.f;
        w.y = (y0ok && x1ok) ? m * wy0 * wx1 : 0.f;
        w.z = (y1ok && x0ok) ? m * wy1 * wx0 : 0.f;
        w.w = (y1ok && x1ok) ? m * wy1 * wx1 : 0.f;
        s_tw[i] = w;
      }
    }
  }
  __syncthreads();   // s_ti/s_tw ready (read-only hereafter)

  const uint4 z4 = make_uint4(0u, 0u, 0u, 0u);

  floatx4 acc[8];
#pragma unroll
  for (int i = 0; i < 8; ++i) acc[i] = (floatx4){0.f, 0.f, 0.f, 0.f};

  uint4 traw[12];   // [kk][tap]
  {
    int cbase = quad * 8;                       // phase 0: cg=0
#pragma unroll
    for (int kk = 0; kk < 3; ++kk) {
      ushort4 ti = s_ti[(kk << 6) + px];        // phase 0: k = kk
      float4 twn = s_tw[(kk << 6) + px];
      uint4 t0 = z4, t1 = z4, t2 = z4, t3 = z4;
      if (__any(twn.x != 0.f)) t0 = *(const uint4*)&xb[(size_t)ti.x * 256 + cbase];
      if (__any(twn.y != 0.f)) t1 = *(const uint4*)&xb[(size_t)ti.y * 256 + cbase];
      if (__any(twn.z != 0.f)) t2 = *(const uint4*)&xb[(size_t)ti.z * 256 + cbase];
      if (__any(twn.w != 0.f)) t3 = *(const uint4*)&xb[(size_t)ti.w * 256 + cbase];
      traw[kk * 4 + 0] = t0; traw[kk * 4 + 1] = t1;
      traw[kk * 4 + 2] = t2; traw[kk * 4 + 3] = t3;
    }
  }
  {  // glds W(phase 0) -> buf 0
    const unsigned short* wsrc = wt;
#pragma unroll
    for (int i = 0; i < 6; ++i) {
      int blk = wvx * 6 + i;
      glds16(wsrc + (size_t)blk * 512 + lane * 8, &sW[blk * 512]);
    }
  }
  __syncthreads();   // buf0 complete (vmcnt drain) + taps in regs

  int lofs = lane * 8;   // lane-linear A-frag offset (ushorts)

  for (int phase = 0; phase < 24; ++phase) {
    unsigned short* buf = sW + (phase & 1) * 12288;
    unsigned short* nbuf = sW + ((phase + 1) & 1) * 12288;
    if (phase < 23) {
      const unsigned short* wsrc = wt + (size_t)(phase + 1) * 12288;
#pragma unroll
      for (int i = 0; i < 6; ++i) {
        int blk = wvx * 6 + i;
        glds16(wsrc + (size_t)blk * 512 + lane * 8, &nbuf[blk * 512]);
      }
    }
    int nphase = phase + 1;
    int ncbase = (nphase / 3) * 32 + quad * 8;

#pragma unroll
    for (int kk = 0; kk < 3; ++kk) {
      int k = (phase % 3) * 3 + kk;
      float4 tw = s_tw[(k << 6) + px];
      union { uint4 u; short8 s; } x0, x1, x2, x3;
      x0.u = traw[kk * 4 + 0]; x1.u = traw[kk * 4 + 1];
      x2.u = traw[kk * 4 + 2]; x3.u = traw[kk * 4 + 3];
      if (phase < 23) {
        int nk = (nphase % 3) * 3 + kk;
        ushort4 ti = s_ti[(nk << 6) + px];
        float4 twn = s_tw[(nk << 6) + px];
        uint4 t0 = z4, t1 = z4, t2 = z4, t3 = z4;
        if (__any(twn.x != 0.f)) t0 = *(const uint4*)&xb[(size_t)ti.x * 256 + ncbase];
        if (__any(twn.y != 0.f)) t1 = *(const uint4*)&xb[(size_t)ti.y * 256 + ncbase];
        if (__any(twn.z != 0.f)) t2 = *(const uint4*)&xb[(size_t)ti.z * 256 + ncbase];
        if (__any(twn.w != 0.f)) t3 = *(const uint4*)&xb[(size_t)ti.w * 256 + ncbase];
        traw[kk * 4 + 0] = t0; traw[kk * 4 + 1] = t1;
        traw[kk * 4 + 2] = t2; traw[kk * 4 + 3] = t3;
      }
      float r[8];
#pragma unroll
      for (int j = 0; j < 8; ++j) r[j] = tw.x * bf2f((unsigned short)x0.s[j]);
      if (__any(tw.y != 0.f)) {
#pragma unroll
        for (int j = 0; j < 8; ++j) r[j] += tw.y * bf2f((unsigned short)x1.s[j]);
      }
      if (__any(tw.z != 0.f)) {
#pragma unroll
        for (int j = 0; j < 8; ++j) r[j] += tw.z * bf2f((unsigned short)x2.s[j]);
      }
      if (__any(tw.w != 0.f)) {
#pragma unroll
        for (int j = 0; j < 8; ++j) r[j] += tw.w * bf2f((unsigned short)x3.s[j]);
      }
      union { uint4 u; short8 s; } bu;
      bu.u = make_uint4(bf16h(r[0]) | (bf16h(r[1]) << 16), bf16h(r[2]) | (bf16h(r[3]) << 16),
                        bf16h(r[4]) | (bf16h(r[5]) << 16), bf16h(r[6]) | (bf16h(r[7]) << 16));
      const unsigned short* bk = buf + kk * 4096 + lofs;
#pragma unroll
      for (int ot = 0; ot < 8; ++ot) {
        short8 af = *(const short8*)&bk[ot * 512];
        acc[ot] = __builtin_amdgcn_mfma_f32_16x16x32_bf16(af, bu.s, acc[ot], 0, 0, 0);
      }
    }
    __syncthreads();  // drains glds(next) + all waves done reading buf
  }

  // epilogue: BN+ReLU then R[slot][px] = sum_o v[o][slot]*yv, reduced over quads
  float* sv = (float*)sW;          // 128*17 vtab (stride 17: conflict-free) + bn
  float* sbn = sv + 2176;
  for (int i = t; i < 2048; i += 256) sv[(i >> 4) * 17 + (i & 15)] = vtab[i];
  if (t < 256) sbn[t] = bntab[t];
  __syncthreads();

  float rpart[16];
#pragma unroll
  for (int i = 0; i < 16; ++i) rpart[i] = 0.f;
#pragma unroll
  for (int ot = 0; ot < 8; ++ot)
#pragma unroll
    for (int r = 0; r < 4; ++r) {
      int o = ot * 16 + quad * 4 + r;
      float yv = fmaxf(acc[ot][r] * sbn[o] + sbn[128 + o], 0.f);
      const float* vp = &sv[o * 17];
#pragma unroll
      for (int tt = 0; tt < 16; ++tt) rpart[tt] += vp[tt] * yv;
    }
#pragma unroll
  for (int tt = 0; tt < 16; ++tt) {
    rpart[tt] += __shfl_xor(rpart[tt], 16, 64);
    rpart[tt] += __shfl_xor(rpart[tt], 32, 64);
  }
#pragma unroll
  for (int j = 0; j < 4; ++j) {
    int slot = quad * 4 + j;
    R[(((size_t)(b * 16 + slot)) << 12) + row * 64 + px] = rpart[slot];
  }
}

// ---------------------------------------------------------------------------
// K3: upsample+1x1+sigmoid from R planes: 4 coalesced loads + sigmoid
// ---------------------------------------------------------------------------
__global__ __launch_bounds__(256) void k_upb(
    const float* __restrict__ R, float* __restrict__ out) {
  int b = blockIdx.x & 7, sub = blockIdx.x >> 3;
  int inner = sub * 256 + threadIdx.x;        // 0..16383
  int X = inner & 127, Y = inner >> 7;        // Y 0..127
  int i0, wu0, wu1, j0, wv0, wv1;
  if (Y & 1) { i0 = (Y - 1) >> 1; wu0 = 2; wu1 = 0; }
  else       { i0 = (Y - 2) / 2;  wu0 = 3; wu1 = 1; }
  if (X & 1) { j0 = (X - 1) >> 1; wv0 = 2; wv1 = 0; }
  else       { j0 = (X - 2) / 2;  wv0 = 3; wv1 = 1; }
  int i1 = i0 + 1, j1 = j0 + 1;
  float mi0 = ((unsigned)i0 < 64u) ? 1.f : 0.f;
  float mi1 = ((unsigned)i1 < 64u) ? 1.f : 0.f;
  float mj0 = ((unsigned)j0 < 64u) ? 1.f : 0.f;
  float mj1 = ((unsigned)j1 < 64u) ? 1.f : 0.f;
  int i0c = min(max(i0, 0), 63), i1c = min(max(i1, 0), 63);
  int j0c = min(max(j0, 0), 63), j1c = min(max(j1, 0), 63);
  const float* Rb = R + (((size_t)b) << 16);   // b*16*4096
  float s = mi0 * mj0 * Rb[((wu0 * 4 + wv0) << 12) + (i0c << 6) + j0c] +
            mi0 * mj1 * Rb[((wu0 * 4 + wv1) << 12) + (i0c << 6) + j1c] +
            mi1 * mj0 * Rb[((wu1 * 4 + wv0) << 12) + (i1c << 6) + j0c] +
            mi1 * mj1 * Rb[((wu1 * 4 + wv1) << 12) + (i1c << 6) + j1c];
  out[(b << 14) + inner] = 1.f / (1.f + __expf(-s));
}

// ---------------------------------------------------------------------------
extern "C" void kernel_launch(void* const* d_in, const int* in_sizes, int n_in,
                              void* d_out, int out_size, void* d_ws, size_t ws_size,
                              hipStream_t stream) {
  const float* x        = (const float*)d_in[0];
  const float* w_dcn    = (const float*)d_in[1];
  const float* b_dcn    = (const float*)d_in[2];
  const float* w_off    = (const float*)d_in[3];
  const float* b_off    = (const float*)d_in[4];
  const float* bn_gamma = (const float*)d_in[5];
  const float* bn_beta  = (const float*)d_in[6];
  const float* bn_mean  = (const float*)d_in[7];
  const float* bn_var   = (const float*)d_in[8];
  const float* w_up     = (const float*)d_in[9];
  const float* w_1x1    = (const float*)d_in[10];
  float* out = (float*)d_out;

  // ws layout in FLOAT units:
  float* ws = (float*)d_ws;
  unsigned short* xT     = (unsigned short*)ws;                    // 8388608 ush
  unsigned short* wt_dcn = (unsigned short*)(ws + 4194304);        //  294912 ush
  unsigned short* wt_off = (unsigned short*)(ws + 4341760);        //   73728 ush
  float* vtab            = ws + 4378624;                           //    2048 f
  float* bntab           = ws + 4380672;                           //     256 f
  unsigned int* offflags = (unsigned int*)(ws + 4380928);          //    1152 u32
  float* R               = ws + 4823296;                           //  524288 f

  k_pre<<<1152, 256, 0, stream>>>(x, w_dcn, w_off, b_dcn, bn_gamma, bn_beta,
                                  bn_mean, bn_var, w_up, w_1x1,
                                  xT, wt_dcn, wt_off, vtab, bntab, offflags);
  k_dcnu<<<512, 256, 0, stream>>>(xT, wt_dcn, b_off, vtab, bntab, offflags, R);
  k_dcng<<<512, 256, 0, stream>>>(xT, wt_dcn, wt_off, b_off, vtab, bntab,
                                  offflags, R);
  k_upb<<<512, 256, 0, stream>>>(R, out);
}

// Round 9
// 128.119 us; speedup vs baseline: 1.5896x; 1.1234x over previous
//
#include <hip/hip_runtime.h>
#include <math.h>

typedef __attribute__((ext_vector_type(8))) short short8;
typedef __attribute__((ext_vector_type(4))) float floatx4;

__device__ __forceinline__ unsigned short bf16r(float f) {
  union { float f; unsigned int u; } v; v.f = f;
  unsigned int u = v.u;
  return (unsigned short)((u + 0x7fffu + ((u >> 16) & 1u)) >> 16);
}
// round-half-up pack (sampling path; 2 ops)
__device__ __forceinline__ unsigned int bf16h(float f) {
  union { float f; unsigned int u; } v; v.f = f;
  return (v.u + 0x8000u) >> 16;
}
__device__ __forceinline__ float bf2f(unsigned int u) {
  union { unsigned int u; float f; } v; v.u = u << 16; return v.f;
}
// async global->LDS DMA, 16B/lane; LDS dst = wave-uniform base + lane*16,
// GLOBAL source address is per-lane (may scatter).
__device__ __forceinline__ void glds16(const void* g, void* l) {
  __builtin_amdgcn_global_load_lds(
      (const __attribute__((address_space(1))) unsigned int*)g,
      (__attribute__((address_space(3))) unsigned int*)l, 16, 0, 0);
}

// ---------------------------------------------------------------------------
// K0 (MERGED prep + xT): weight prep (bf16, lane-linear MFMA-frag layouts),
// fused tables, w_off-nonzero flags, and the x->xT transpose.
// ---------------------------------------------------------------------------
__global__ __launch_bounds__(256) void k_pre(
    const float* __restrict__ x,
    const float* __restrict__ w_dcn, const float* __restrict__ w_off,
    const float* __restrict__ b_dcn,
    const float* __restrict__ bn_g, const float* __restrict__ bn_b,
    const float* __restrict__ bn_m, const float* __restrict__ bn_v,
    const float* __restrict__ w_up, const float* __restrict__ w1x1,
    unsigned short* __restrict__ xT,
    unsigned short* __restrict__ wt_dcn, unsigned short* __restrict__ wt_off,
    float* __restrict__ vtab, float* __restrict__ bntab,
    unsigned int* __restrict__ offflags) {
  __shared__ unsigned short sx[32 * 264];
  int e = blockIdx.x * 256 + threadIdx.x;
  if (e < 294912) {
    int s = e >> 12;            // s = cg*9 + k  (72 tiles of 4096 ush)
    int r = e & 4095;
    int ot = r >> 9;            // 8 output-tiles of 512 ush
    int lane = (r >> 3) & 63;   // wave lane this element feeds
    int j = e & 7;
    int l15 = lane & 15, quad = lane >> 4;
    int o = ot * 16 + l15;
    int k = s % 9, cg = s / 9;
    int c = cg * 32 + quad * 8 + j;
    wt_dcn[e] = bf16r(w_dcn[(o * 256 + c) * 9 + k]);
  }
  bool nz = false;
  if (e < 73728) {
    int cg = e / 9216;
    int r = e % 9216;
    int frag = r >> 9;          // 18 frags: (k,ot)
    int k = frag >> 1, ot = frag & 1;
    int lane = (r >> 3) & 63, j = e & 7;
    int l15 = lane & 15, quad = lane >> 4;
    int oc = ot * 16 + l15;
    int c = cg * 32 + quad * 8 + j;
    float wv = (oc < 27) ? w_off[(oc * 256 + c) * 9 + k] : 0.f;
    wt_off[e] = bf16r(wv);
    nz = (wv != 0.f);
  }
  unsigned long long ba = __ballot(nz);
  if (blockIdx.x < 288 && (threadIdx.x & 63) == 0)
    offflags[blockIdx.x * 4 + (threadIdx.x >> 6)] = (ba != 0ull) ? 1u : 0u;
  if (e < 2048) {
    int o = e >> 4;
    vtab[e] = w1x1[o] * w_up[e];
  }
  if (e < 128) {
    float g = bn_g[e] * rsqrtf(bn_v[e] + 1e-5f);
    bntab[e] = g;
    bntab[128 + e] = (b_dcn[e] - bn_m[e]) * g + bn_b[e];
  }
  if (blockIdx.x < 1024) {
    int b = blockIdx.x & 7, px0 = ((blockIdx.x >> 3) & 127) * 32;
    int t = threadIdx.x;
    int px = t & 31, cg = t >> 5;
    const float* xsrc = x + (((size_t)(b * 256 + cg * 32)) << 12) + px0 + px;
#pragma unroll
    for (int cc = 0; cc < 32; ++cc)
      sx[px * 264 + cg * 32 + cc] = bf16r(xsrc[(size_t)cc << 12]);
    __syncthreads();
#pragma unroll
    for (int j = 0; j < 4; ++j) {
      int unit = t + j * 256;
      int p = unit >> 5, chunk = unit & 31;
      uint4 v = *(const uint4*)&sx[p * 264 + chunk * 8];
      *(uint4*)&xT[((size_t)((b << 12) + px0 + p)) * 256 + chunk * 8] = v;
    }
  }
}

// ---------------------------------------------------------------------------
// K2u (ULTRA): runs iff w_off == 0 AND b_off == 0.  om = 0 exactly ->
// offsets 0, mask = 0.5 exactly; 0.5 folds into BN scale (pow2-exact).
// Main loop = plain 3x3 conv via MFMA.  R9 redesign (LDS-BW + VMEM):
//  - per phase ky is FIXED (k = kset*3+kx), so B = one xT row x 32ch = 4 KB:
//    staged into LDS by ONE coalesced glds/wave (double-buffered), replacing
//    3 scattered gathers/wave/phase.  kx = px-shift on the LDS read with
//    per-lane edge zero-select (bit-identical B values).
//  - wave owns {4 ot x 2 pxg} (was {8 ot x 1 pxg}): per-phase LDS reads
//    18 b128 vs 24, cutting block LDS-read volume 96->72 KB/phase (the
//    invisible saturated pipe: 8 waves streaming W at b128 ~ 80% LDS busy).
//  - epilogue: 2 waves share a px range -> cross-wave sred[64][17] reduce.
// XCD-swizzled: batch b -> XCD b.
// ---------------------------------------------------------------------------
__global__ __launch_bounds__(256, 2) void k_dcnu(
    const unsigned short* __restrict__ xT, const unsigned short* __restrict__ wt,
    const float* __restrict__ b_off, const float* __restrict__ vtab,
    const float* __restrict__ bntab, const unsigned int* __restrict__ offflags,
    float* __restrict__ R) {
  int b = blockIdx.x & 7, row = blockIdx.x >> 3;
  __shared__ unsigned short sW[2 * 12288];   // 49152 B (W dbuf; epi tables)
  __shared__ unsigned short sB[2 * 2048];    // 2 x 4 KB B-row dbuf
  __shared__ float sred[64 * 17];            // 4352 B epilogue reduce
  __shared__ unsigned int s_fl[8];
  int t = threadIdx.x, lane = t & 63, wvx = t >> 6;
  int l15 = lane & 15, quad = lane >> 4;
  int oh = wvx >> 1;                         // ot-half: ot in [oh*4, oh*4+4)
  int ph = wvx & 1;                          // px-half: pxg in {ph*2, ph*2+1}
  const unsigned short* xb = xT + (((size_t)b) << 12) * 256;
  const short8 zz = {0, 0, 0, 0, 0, 0, 0, 0};

  // ---- flags: ultra iff all w_off == 0 AND all b_off == 0 -----------------
  {
    unsigned int a = 0;
    for (int i = t; i < 1152; i += 256) a |= offflags[i];
    unsigned int bo = (lane < 27 && b_off[lane] != 0.f) ? 1u : 0u;
    a = __any(a != 0u) ? 1u : 0u;
    bo = __any(bo != 0u) ? 1u : 0u;
    if (lane == 0) { s_fl[wvx] = a; s_fl[4 + wvx] = bo; }
  }
  __syncthreads();
  if ((s_fl[0] | s_fl[1] | s_fl[2] | s_fl[3] |
       s_fl[4] | s_fl[5] | s_fl[6] | s_fl[7]) != 0u)
    return;   // not ultra: k_dcng handles this case

  floatx4 acc[4][2];
#pragma unroll
  for (int i = 0; i < 4; ++i)
#pragma unroll
    for (int j = 0; j < 2; ++j) acc[i][j] = (floatx4){0.f, 0.f, 0.f, 0.f};

  // ---- prologue: stage W(phase 0) + B-row(phase 0) ------------------------
#pragma unroll
  for (int i = 0; i < 6; ++i) {
    int blk = wvx * 6 + i;
    glds16(wt + (size_t)blk * 512 + lane * 8, &sW[blk * 512]);
  }
  {   // phase 0: cg=0, kset=0 -> rowk = row-1 (invalid for row 0)
    int rowk = row - 1;
    if (rowk >= 0)
      glds16(xb + (size_t)(rowk * 64 + wvx * 16 + (lane >> 2)) * 256 + (lane & 3) * 8,
             &sB[wvx * 512]);
  }
  __syncthreads();

  for (int phase = 0; phase < 24; ++phase) {
    const unsigned short* bufW = sW + (phase & 1) * 12288;
    const unsigned short* bufB = sB + (phase & 1) * 2048;
    // stage next phase (W 24 KB + B-row 4 KB), overlaps compute below
    if (phase < 23) {
      int np = phase + 1;
      unsigned short* nW = sW + (np & 1) * 12288;
      const unsigned short* wsrc = wt + (size_t)np * 12288;
#pragma unroll
      for (int i = 0; i < 6; ++i) {
        int blk = wvx * 6 + i;
        glds16(wsrc + (size_t)blk * 512 + lane * 8, &nW[blk * 512]);
      }
      int rowk_n = row + np % 3 - 1;
      if ((unsigned)rowk_n < 64u)
        glds16(xb + (size_t)(rowk_n * 64 + wvx * 16 + (lane >> 2)) * 256 +
                   (np / 3) * 32 + (lane & 3) * 8,
               &sB[((np & 1) * 2048) + wvx * 512]);
    }
    int rowk = row + phase % 3 - 1;
    if ((unsigned)rowk < 64u) {     // invalid row -> contribution exactly 0
#pragma unroll
      for (int kx = 0; kx < 3; ++kx) {
        // B fragments for this wave's 2 px-groups (px-shift kx-1 in LDS)
        short8 bf[2];
#pragma unroll
        for (int pg = 0; pg < 2; ++pg) {
          int pxe = (ph * 2 + pg) * 16 + l15 + kx - 1;
          bool v = (unsigned)pxe < 64u;
          int pxc = min(max(pxe, 0), 63);
          union { uint4 u; short8 s; } bb;
          bb.u = *(const uint4*)&bufB[pxc * 32 + quad * 8];
          bf[pg] = v ? bb.s : zz;
        }
        const unsigned short* ak = bufW + kx * 4096 + (oh * 4) * 512 + lane * 8;
#pragma unroll
        for (int oi = 0; oi < 4; ++oi) {
          short8 af = *(const short8*)&ak[oi * 512];
          acc[oi][0] = __builtin_amdgcn_mfma_f32_16x16x32_bf16(af, bf[0], acc[oi][0], 0, 0, 0);
          acc[oi][1] = __builtin_amdgcn_mfma_f32_16x16x32_bf16(af, bf[1], acc[oi][1], 0, 0, 0);
        }
      }
    }
    __syncthreads();  // drains glds(next) + all waves done reading buffers
  }

  // ---- epilogue: BN+ReLU (0.5 folded), v-table contraction, store R -------
  float* sv = (float*)sW;          // 128*17 vtab (stride 17) + bn
  float* sbn = sv + 2176;
  for (int i = t; i < 2048; i += 256) sv[(i >> 4) * 17 + (i & 15)] = vtab[i];
  if (t < 256) sbn[t] = bntab[t];
  __syncthreads();

  float rpart[2][16];
#pragma unroll
  for (int pg = 0; pg < 2; ++pg)
#pragma unroll
    for (int i = 0; i < 16; ++i) rpart[pg][i] = 0.f;
#pragma unroll
  for (int oi = 0; oi < 4; ++oi)
#pragma unroll
    for (int r = 0; r < 4; ++r) {
      int o = (oh * 4 + oi) * 16 + quad * 4 + r;
      float g = 0.5f * sbn[o], bta = sbn[128 + o];
      const float* vp = &sv[o * 17];
#pragma unroll
      for (int pg = 0; pg < 2; ++pg) {
        float yv = fmaxf(acc[oi][pg][r] * g + bta, 0.f);
#pragma unroll
        for (int tt = 0; tt < 16; ++tt) rpart[pg][tt] += vp[tt] * yv;
      }
    }
#pragma unroll
  for (int pg = 0; pg < 2; ++pg)
#pragma unroll
    for (int tt = 0; tt < 16; ++tt) {
      rpart[pg][tt] += __shfl_xor(rpart[pg][tt], 16, 64);
      rpart[pg][tt] += __shfl_xor(rpart[pg][tt], 32, 64);
    }
  // cross-wave (ot-half) reduce via sred[px][17-padded slots]
  if (oh == 0 && lane < 16) {
#pragma unroll
    for (int pg = 0; pg < 2; ++pg)
#pragma unroll
      for (int tt = 0; tt < 16; ++tt)
        sred[((ph * 2 + pg) * 16 + lane) * 17 + tt] = rpart[pg][tt];
  }
  __syncthreads();
  if (oh == 1 && lane < 16) {
#pragma unroll
    for (int pg = 0; pg < 2; ++pg)
#pragma unroll
      for (int tt = 0; tt < 16; ++tt)
        sred[((ph * 2 + pg) * 16 + lane) * 17 + tt] += rpart[pg][tt];
  }
  __syncthreads();
  // store: 1024 f32 over 256 threads, coalesced in px
#pragma unroll
  for (int j = 0; j < 4; ++j) {
    int idx = t + j * 256;
    int slot = idx >> 6, pxs = idx & 63;
    R[(((size_t)(b * 16 + slot)) << 12) + row * 64 + pxs] = sred[pxs * 17 + slot];
  }
}

// ---------------------------------------------------------------------------
// K2g (GENERAL, R7 structure): handles w_off != 0 (full offset conv) or
// b_off != 0 (uniform-offset taps).  Early-returns when ultra is responsible.
// ---------------------------------------------------------------------------
__global__ __launch_bounds__(256, 2) void k_dcng(
    const unsigned short* __restrict__ xT, const unsigned short* __restrict__ wt,
    const unsigned short* __restrict__ wtoff, const float* __restrict__ b_off,
    const float* __restrict__ vtab, const float* __restrict__ bntab,
    const unsigned int* __restrict__ offflags, float* __restrict__ R) {
  int b = blockIdx.x & 7, row = blockIdx.x >> 3;
  __shared__ unsigned short sW[2 * 12288];   // 49152 B; prologue-A: 2 x 9216-ush
  __shared__ ushort4 s_ti[576];              // 4608 B; first 3456 B = som (bf16)
  __shared__ float4 s_tw[576];               // 9216 B
  __shared__ unsigned int s_fl[8];
  int t = threadIdx.x, lane = t & 63, wvx = t >> 6;
  int l15 = lane & 15, quad = lane >> 4;
  int px = wvx * 16 + l15;
  const unsigned short* xb = xT + (((size_t)b) << 12) * 256;
  const short8 zz = {0, 0, 0, 0, 0, 0, 0, 0};
  unsigned short* som = (unsigned short*)s_ti;   // 27*64 bf16 = 3456 B

  // ---- flags --------------------------------------------------------------
  {
    unsigned int a = 0;
    for (int i = t; i < 1152; i += 256) a |= offflags[i];
    unsigned int bo = (lane < 27 && b_off[lane] != 0.f) ? 1u : 0u;
    a = __any(a != 0u) ? 1u : 0u;
    bo = __any(bo != 0u) ? 1u : 0u;
    if (lane == 0) { s_fl[wvx] = a; s_fl[4 + wvx] = bo; }
  }
  __syncthreads();
  const bool offnz = (s_fl[0] | s_fl[1] | s_fl[2] | s_fl[3]) != 0u;
  const bool bofnz = (s_fl[4] | s_fl[5] | s_fl[6] | s_fl[7]) != 0u;
  if (!offnz && !bofnz) return;   // ultra: k_dcnu handles

  if (!offnz) {
    // warming sweep (b_off-only fast path)
    int wr0 = max(row - 1, 0), wr1 = min(row + 1, 63);
    for (int rr = wr0; rr <= wr1; ++rr) {
      const uint4* src = (const uint4*)(xb + ((size_t)(rr << 6)) * 256);
#pragma unroll
      for (int i = 0; i < 8; ++i) {
        uint4 v = src[t + (i << 8)];
        asm volatile("" :: "v"(v.x), "v"(v.y), "v"(v.z), "v"(v.w));
      }
    }
  }

  // ---- prologue-A (slow path only): offset conv for (b,row) ---------------
  if (offnz) {
    int pixk[9]; bool vkk[9];
#pragma unroll
    for (int k = 0; k < 9; ++k) {
      int yy = row + k / 3 - 1, xx = px + k % 3 - 1;
      vkk[k] = ((unsigned)yy < 64u) & ((unsigned)xx < 64u);
      pixk[k] = vkk[k] ? (yy * 64 + xx) : 0;
    }
    floatx4 oacc[2];
    oacc[0] = (floatx4){0.f, 0.f, 0.f, 0.f};
    oacc[1] = (floatx4){0.f, 0.f, 0.f, 0.f};

#pragma unroll
    for (int i = 0; i < 5; ++i) {
      int frag = wvx + i * 4;
      if (frag < 18)
        glds16(wtoff + (size_t)frag * 512 + lane * 8, &sW[frag * 512]);
    }
    __syncthreads();   // buf0 weights ready

    for (int cg = 0; cg < 8; ++cg) {
      unsigned short* buf = sW + (cg & 1) * 9216;
      int cb = cg * 32 + quad * 8;
      short8 bx[9];
#pragma unroll
      for (int k = 0; k < 9; ++k) {
        short8 v = *(const short8*)&xb[(size_t)pixk[k] * 256 + cb];
        bx[k] = vkk[k] ? v : zz;
      }
      if (cg < 7) {
        const unsigned short* wsrc = wtoff + (size_t)(cg + 1) * 9216;
        unsigned short* nbuf = sW + ((cg + 1) & 1) * 9216;
#pragma unroll
        for (int i = 0; i < 5; ++i) {
          int frag = wvx + i * 4;
          if (frag < 18)
            glds16(wsrc + (size_t)frag * 512 + lane * 8, &nbuf[frag * 512]);
        }
      }
#pragma unroll
      for (int k = 0; k < 9; ++k) {
        short8 a0 = *(const short8*)&buf[(k * 2 + 0) * 512 + lane * 8];
        short8 a1 = *(const short8*)&buf[(k * 2 + 1) * 512 + lane * 8];
        oacc[0] = __builtin_amdgcn_mfma_f32_16x16x32_bf16(a0, bx[k], oacc[0], 0, 0, 0);
        oacc[1] = __builtin_amdgcn_mfma_f32_16x16x32_bf16(a1, bx[k], oacc[1], 0, 0, 0);
      }
      __syncthreads();
    }
#pragma unroll
    for (int ot = 0; ot < 2; ++ot)
#pragma unroll
      for (int r = 0; r < 4; ++r) {
        int o = ot * 16 + quad * 4 + r;
        if (o < 27) som[o * 64 + px] = bf16r(oacc[ot][r] + b_off[o]);
      }
    __syncthreads();   // som complete
  }

  // ---- prologue-B: taps = 4 clamped pixel indices + 4 weights per (k,px) ---
  {
    float to1[3], to2[3], tmv[3];
    if (offnz) {
#pragma unroll
      for (int ii = 0; ii < 3; ++ii) {
        int i = t + ii * 256;
        if (i < 576) {
          int k = i >> 6, p = i & 63;
          to1[ii] = bf2f(som[k * 64 + p]);
          to2[ii] = bf2f(som[(9 + k) * 64 + p]);
          tmv[ii] = bf2f(som[(18 + k) * 64 + p]);
        }
      }
      __syncthreads();   // all som reads done before s_ti overwrites
    } else {
#pragma unroll
      for (int ii = 0; ii < 3; ++ii) {
        int i = t + ii * 256;
        if (i < 576) {
          int k = i >> 6;
          to1[ii] = bf2f(bf16r(b_off[k]));        // == bf16r(0 + b_off)
          to2[ii] = bf2f(bf16r(b_off[9 + k]));
          tmv[ii] = bf2f(bf16r(b_off[18 + k]));
        }
      }
    }
#pragma unroll
    for (int ii = 0; ii < 3; ++ii) {
      int i = t + ii * 256;
      if (i < 576) {
        int k = i >> 6, p = i & 63;
        float m = 1.f / (1.f + __expf(-tmv[ii]));
        float py = (float)(row + k / 3 - 1) + to1[ii];
        float pxf = (float)(p + (k % 3) - 1) + to2[ii];
        float fy = floorf(py), fx = floorf(pxf);
        int iy = (int)fy, ix = (int)fx;
        float wy1 = py - fy, wy0 = 1.f - wy1;
        float wx1 = pxf - fx, wx0 = 1.f - wx1;
        bool y0ok = (iy >= 0) & (iy < 64), y1ok = (iy >= -1) & (iy < 63);
        bool x0ok = (ix >= 0) & (ix < 64), x1ok = (ix >= -1) & (ix < 63);
        int iy0 = min(max(iy, 0), 63), iy1 = min(max(iy + 1, 0), 63);
        int ix0 = min(max(ix, 0), 63), ix1 = min(max(ix + 1, 0), 63);
        s_ti[i] = make_ushort4((unsigned short)(iy0 * 64 + ix0), (unsigned short)(iy0 * 64 + ix1),
                               (unsigned short)(iy1 * 64 + ix0), (unsigned short)(iy1 * 64 + ix1));
        float4 w;
        w.x = (y0ok && x0ok) ? m * wy0 * wx0 : 0.f;
        w.y = (y0ok && x1ok) ? m * wy0 * wx1 : 0.f;
        w.z = (y1ok && x0ok) ? m * wy1 * wx0 : 0.f;
        w.w = (y1ok && x1ok) ? m * wy1 * wx1 : 0.f;
        s_tw[i] = w;
      }
    }
  }
  __syncthreads();   // s_ti/s_tw ready (read-only hereafter)

  const uint4 z4 = make_uint4(0u, 0u, 0u, 0u);

  floatx4 acc[8];
#pragma unroll
  for (int i = 0; i < 8; ++i) acc[i] = (floatx4){0.f, 0.f, 0.f, 0.f};

  uint4 traw[12];   // [kk][tap]
  {
    int cbase = quad * 8;                       // phase 0: cg=0
#pragma unroll
    for (int kk = 0; kk < 3; ++kk) {
      ushort4 ti = s_ti[(kk << 6) + px];        // phase 0: k = kk
      float4 twn = s_tw[(kk << 6) + px];
      uint4 t0 = z4, t1 = z4, t2 = z4, t3 = z4;
      if (__any(twn.x != 0.f)) t0 = *(const uint4*)&xb[(size_t)ti.x * 256 + cbase];
      if (__any(twn.y != 0.f)) t1 = *(const uint4*)&xb[(size_t)ti.y * 256 + cbase];
      if (__any(twn.z != 0.f)) t2 = *(const uint4*)&xb[(size_t)ti.z * 256 + cbase];
      if (__any(twn.w != 0.f)) t3 = *(const uint4*)&xb[(size_t)ti.w * 256 + cbase];
      traw[kk * 4 + 0] = t0; traw[kk * 4 + 1] = t1;
      traw[kk * 4 + 2] = t2; traw[kk * 4 + 3] = t3;
    }
  }
  {  // glds W(phase 0) -> buf 0
    const unsigned short* wsrc = wt;
#pragma unroll
    for (int i = 0; i < 6; ++i) {
      int blk = wvx * 6 + i;
      glds16(wsrc + (size_t)blk * 512 + lane * 8, &sW[blk * 512]);
    }
  }
  __syncthreads();   // buf0 complete (vmcnt drain) + taps in regs

  int lofs = lane * 8;   // lane-linear A-frag offset (ushorts)

  for (int phase = 0; phase < 24; ++phase) {
    unsigned short* buf = sW + (phase & 1) * 12288;
    unsigned short* nbuf = sW + ((phase + 1) & 1) * 12288;
    if (phase < 23) {
      const unsigned short* wsrc = wt + (size_t)(phase + 1) * 12288;
#pragma unroll
      for (int i = 0; i < 6; ++i) {
        int blk = wvx * 6 + i;
        glds16(wsrc + (size_t)blk * 512 + lane * 8, &nbuf[blk * 512]);
      }
    }
    int nphase = phase + 1;
    int ncbase = (nphase / 3) * 32 + quad * 8;

#pragma unroll
    for (int kk = 0; kk < 3; ++kk) {
      int k = (phase % 3) * 3 + kk;
      float4 tw = s_tw[(k << 6) + px];
      union { uint4 u; short8 s; } x0, x1, x2, x3;
      x0.u = traw[kk * 4 + 0]; x1.u = traw[kk * 4 + 1];
      x2.u = traw[kk * 4 + 2]; x3.u = traw[kk * 4 + 3];
      if (phase < 23) {
        int nk = (nphase % 3) * 3 + kk;
        ushort4 ti = s_ti[(nk << 6) + px];
        float4 twn = s_tw[(nk << 6) + px];
        uint4 t0 = z4, t1 = z4, t2 = z4, t3 = z4;
        if (__any(twn.x != 0.f)) t0 = *(const uint4*)&xb[(size_t)ti.x * 256 + ncbase];
        if (__any(twn.y != 0.f)) t1 = *(const uint4*)&xb[(size_t)ti.y * 256 + ncbase];
        if (__any(twn.z != 0.f)) t2 = *(const uint4*)&xb[(size_t)ti.z * 256 + ncbase];
        if (__any(twn.w != 0.f)) t3 = *(const uint4*)&xb[(size_t)ti.w * 256 + ncbase];
        traw[kk * 4 + 0] = t0; traw[kk * 4 + 1] = t1;
        traw[kk * 4 + 2] = t2; traw[kk * 4 + 3] = t3;
      }
      float r[8];
#pragma unroll
      for (int j = 0; j < 8; ++j) r[j] = tw.x * bf2f((unsigned short)x0.s[j]);
      if (__any(tw.y != 0.f)) {
#pragma unroll
        for (int j = 0; j < 8; ++j) r[j] += tw.y * bf2f((unsigned short)x1.s[j]);
      }
      if (__any(tw.z != 0.f)) {
#pragma unroll
        for (int j = 0; j < 8; ++j) r[j] += tw.z * bf2f((unsigned short)x2.s[j]);
      }
      if (__any(tw.w != 0.f)) {
#pragma unroll
        for (int j = 0; j < 8; ++j) r[j] += tw.w * bf2f((unsigned short)x3.s[j]);
      }
      union { uint4 u; short8 s; } bu;
      bu.u = make_uint4(bf16h(r[0]) | (bf16h(r[1]) << 16), bf16h(r[2]) | (bf16h(r[3]) << 16),
                        bf16h(r[4]) | (bf16h(r[5]) << 16), bf16h(r[6]) | (bf16h(r[7]) << 16));
      const unsigned short* bk = buf + kk * 4096 + lofs;
#pragma unroll
      for (int ot = 0; ot < 8; ++ot) {
        short8 af = *(const short8*)&bk[ot * 512];
        acc[ot] = __builtin_amdgcn_mfma_f32_16x16x32_bf16(af, bu.s, acc[ot], 0, 0, 0);
      }
    }
    __syncthreads();  // drains glds(next) + all waves done reading buf
  }

  // epilogue: BN+ReLU then R[slot][px] = sum_o v[o][slot]*yv, reduced over quads
  float* sv = (float*)sW;          // 128*17 vtab (stride 17: conflict-free) + bn
  float* sbn = sv + 2176;
  for (int i = t; i < 2048; i += 256) sv[(i >> 4) * 17 + (i & 15)] = vtab[i];
  if (t < 256) sbn[t] = bntab[t];
  __syncthreads();

  float rpart[16];
#pragma unroll
  for (int i = 0; i < 16; ++i) rpart[i] = 0.f;
#pragma unroll
  for (int ot = 0; ot < 8; ++ot)
#pragma unroll
    for (int r = 0; r < 4; ++r) {
      int o = ot * 16 + quad * 4 + r;
      float yv = fmaxf(acc[ot][r] * sbn[o] + sbn[128 + o], 0.f);
      const float* vp = &sv[o * 17];
#pragma unroll
      for (int tt = 0; tt < 16; ++tt) rpart[tt] += vp[tt] * yv;
    }
#pragma unroll
  for (int tt = 0; tt < 16; ++tt) {
    rpart[tt] += __shfl_xor(rpart[tt], 16, 64);
    rpart[tt] += __shfl_xor(rpart[tt], 32, 64);
  }
#pragma unroll
  for (int j = 0; j < 4; ++j) {
    int slot = quad * 4 + j;
    R[(((size_t)(b * 16 + slot)) << 12) + row * 64 + px] = rpart[slot];
  }
}

// ---------------------------------------------------------------------------
// K3: upsample+1x1+sigmoid from R planes: 4 coalesced loads + sigmoid
// ---------------------------------------------------------------------------
__global__ __launch_bounds__(256) void k_upb(
    const float* __restrict__ R, float* __restrict__ out) {
  int b = blockIdx.x & 7, sub = blockIdx.x >> 3;
  int inner = sub * 256 + threadIdx.x;        // 0..16383
  int X = inner & 127, Y = inner >> 7;        // Y 0..127
  int i0, wu0, wu1, j0, wv0, wv1;
  if (Y & 1) { i0 = (Y - 1) >> 1; wu0 = 2; wu1 = 0; }
  else       { i0 = (Y - 2) / 2;  wu0 = 3; wu1 = 1; }
  if (X & 1) { j0 = (X - 1) >> 1; wv0 = 2; wv1 = 0; }
  else       { j0 = (X - 2) / 2;  wv0 = 3; wv1 = 1; }
  int i1 = i0 + 1, j1 = j0 + 1;
  float mi0 = ((unsigned)i0 < 64u) ? 1.f : 0.f;
  float mi1 = ((unsigned)i1 < 64u) ? 1.f : 0.f;
  float mj0 = ((unsigned)j0 < 64u) ? 1.f : 0.f;
  float mj1 = ((unsigned)j1 < 64u) ? 1.f : 0.f;
  int i0c = min(max(i0, 0), 63), i1c = min(max(i1, 0), 63);
  int j0c = min(max(j0, 0), 63), j1c = min(max(j1, 0), 63);
  const float* Rb = R + (((size_t)b) << 16);   // b*16*4096
  float s = mi0 * mj0 * Rb[((wu0 * 4 + wv0) << 12) + (i0c << 6) + j0c] +
            mi0 * mj1 * Rb[((wu0 * 4 + wv1) << 12) + (i0c << 6) + j1c] +
            mi1 * mj0 * Rb[((wu1 * 4 + wv0) << 12) + (i1c << 6) + j0c] +
            mi1 * mj1 * Rb[((wu1 * 4 + wv1) << 12) + (i1c << 6) + j1c];
  out[(b << 14) + inner] = 1.f / (1.f + __expf(-s));
}

// ---------------------------------------------------------------------------
extern "C" void kernel_launch(void* const* d_in, const int* in_sizes, int n_in,
                              void* d_out, int out_size, void* d_ws, size_t ws_size,
                              hipStream_t stream) {
  const float* x        = (const float*)d_in[0];
  const float* w_dcn    = (const float*)d_in[1];
  const float* b_dcn    = (const float*)d_in[2];
  const float* w_off    = (const float*)d_in[3];
  const float* b_off    = (const float*)d_in[4];
  const float* bn_gamma = (const float*)d_in[5];
  const float* bn_beta  = (const float*)d_in[6];
  const float* bn_mean  = (const float*)d_in[7];
  const float* bn_var   = (const float*)d_in[8];
  const float* w_up     = (const float*)d_in[9];
  const float* w_1x1    = (const float*)d_in[10];
  float* out = (float*)d_out;

  // ws layout in FLOAT units:
  float* ws = (float*)d_ws;
  unsigned short* xT     = (unsigned short*)ws;                    // 8388608 ush
  unsigned short* wt_dcn = (unsigned short*)(ws + 4194304);        //  294912 ush
  unsigned short* wt_off = (unsigned short*)(ws + 4341760);        //   73728 ush
  float* vtab            = ws + 4378624;                           //    2048 f
  float* bntab           = ws + 4380672;                           //     256 f
  unsigned int* offflags = (unsigned int*)(ws + 4380928);          //    1152 u32
  float* R               = ws + 4823296;                           //  524288 f

  k_pre<<<1152, 256, 0, stream>>>(x, w_dcn, w_off, b_dcn, bn_gamma, bn_beta,
                                  bn_mean, bn_var, w_up, w_1x1,
                                  xT, wt_dcn, wt_off, vtab, bntab, offflags);
  k_dcnu<<<512, 256, 0, stream>>>(xT, wt_dcn, b_off, vtab, bntab, offflags, R);
  k_dcng<<<512, 256, 0, stream>>>(xT, wt_dcn, wt_off, b_off, vtab, bntab,
                                  offflags, R);
  k_upb<<<512, 256, 0, stream>>>(R, out);
}

// Round 10
// 125.350 us; speedup vs baseline: 1.6247x; 1.0221x over previous
//
#include <hip/hip_runtime.h>
#include <math.h>

typedef __attribute__((ext_vector_type(8))) short short8;
typedef __attribute__((ext_vector_type(4))) float floatx4;

__device__ __forceinline__ unsigned short bf16r(float f) {
  union { float f; unsigned int u; } v; v.f = f;
  unsigned int u = v.u;
  return (unsigned short)((u + 0x7fffu + ((u >> 16) & 1u)) >> 16);
}
// round-half-up pack (sampling path; 2 ops)
__device__ __forceinline__ unsigned int bf16h(float f) {
  union { float f; unsigned int u; } v; v.f = f;
  return (v.u + 0x8000u) >> 16;
}
__device__ __forceinline__ float bf2f(unsigned int u) {
  union { unsigned int u; float f; } v; v.u = u << 16; return v.f;
}
// async global->LDS DMA, 16B/lane; LDS dst = wave-uniform base + lane*16,
// GLOBAL source address is per-lane (may scatter).
__device__ __forceinline__ void glds16(const void* g, void* l) {
  __builtin_amdgcn_global_load_lds(
      (const __attribute__((address_space(1))) unsigned int*)g,
      (__attribute__((address_space(3))) unsigned int*)l, 16, 0, 0);
}

// ---------------------------------------------------------------------------
// K0 (MERGED prep + xT): weight prep (bf16, lane-linear MFMA-frag layouts),
// fused tables, w_off-nonzero flags, and the x->xT transpose.
// R10: xT branch loads float4 along pixels (8 loads/thread vs 32 scalar) --
// G13, 4x fewer VMEM instrs; LDS layout + read/store phase unchanged.
// ---------------------------------------------------------------------------
__global__ __launch_bounds__(256) void k_pre(
    const float* __restrict__ x,
    const float* __restrict__ w_dcn, const float* __restrict__ w_off,
    const float* __restrict__ b_dcn,
    const float* __restrict__ bn_g, const float* __restrict__ bn_b,
    const float* __restrict__ bn_m, const float* __restrict__ bn_v,
    const float* __restrict__ w_up, const float* __restrict__ w1x1,
    unsigned short* __restrict__ xT,
    unsigned short* __restrict__ wt_dcn, unsigned short* __restrict__ wt_off,
    float* __restrict__ vtab, float* __restrict__ bntab,
    unsigned int* __restrict__ offflags) {
  __shared__ unsigned short sx[32 * 264];
  int e = blockIdx.x * 256 + threadIdx.x;
  if (e < 294912) {
    int s = e >> 12;            // s = cg*9 + k  (72 tiles of 4096 ush)
    int r = e & 4095;
    int ot = r >> 9;            // 8 output-tiles of 512 ush
    int lane = (r >> 3) & 63;   // wave lane this element feeds
    int j = e & 7;
    int l15 = lane & 15, quad = lane >> 4;
    int o = ot * 16 + l15;
    int k = s % 9, cg = s / 9;
    int c = cg * 32 + quad * 8 + j;
    wt_dcn[e] = bf16r(w_dcn[(o * 256 + c) * 9 + k]);
  }
  bool nz = false;
  if (e < 73728) {
    int cg = e / 9216;
    int r = e % 9216;
    int frag = r >> 9;          // 18 frags: (k,ot)
    int k = frag >> 1, ot = frag & 1;
    int lane = (r >> 3) & 63, j = e & 7;
    int l15 = lane & 15, quad = lane >> 4;
    int oc = ot * 16 + l15;
    int c = cg * 32 + quad * 8 + j;
    float wv = (oc < 27) ? w_off[(oc * 256 + c) * 9 + k] : 0.f;
    wt_off[e] = bf16r(wv);
    nz = (wv != 0.f);
  }
  unsigned long long ba = __ballot(nz);
  if (blockIdx.x < 288 && (threadIdx.x & 63) == 0)
    offflags[blockIdx.x * 4 + (threadIdx.x >> 6)] = (ba != 0ull) ? 1u : 0u;
  if (e < 2048) {
    int o = e >> 4;
    vtab[e] = w1x1[o] * w_up[e];
  }
  if (e < 128) {
    float g = bn_g[e] * rsqrtf(bn_v[e] + 1e-5f);
    bntab[e] = g;
    bntab[128 + e] = (b_dcn[e] - bn_m[e]) * g + bn_b[e];
  }
  if (blockIdx.x < 1024) {
    int b = blockIdx.x & 7, px0 = ((blockIdx.x >> 3) & 127) * 32;
    int t = threadIdx.x;
    int q = t & 7, c8 = t >> 3;             // px-quad, channel-octet
    const float* xsrc = x + (((size_t)(b * 256)) << 12) + px0 + q * 4;
#pragma unroll
    for (int i = 0; i < 8; ++i) {
      int c = c8 * 8 + i;
      float4 v4 = *(const float4*)&xsrc[((size_t)c) << 12];
      sx[(q * 4 + 0) * 264 + c] = bf16r(v4.x);
      sx[(q * 4 + 1) * 264 + c] = bf16r(v4.y);
      sx[(q * 4 + 2) * 264 + c] = bf16r(v4.z);
      sx[(q * 4 + 3) * 264 + c] = bf16r(v4.w);
    }
    __syncthreads();
#pragma unroll
    for (int j = 0; j < 4; ++j) {
      int unit = t + j * 256;
      int p = unit >> 5, chunk = unit & 31;
      uint4 v = *(const uint4*)&sx[p * 264 + chunk * 8];
      *(uint4*)&xT[((size_t)((b << 12) + px0 + p)) * 256 + chunk * 8] = v;
    }
  }
}

// ---------------------------------------------------------------------------
// K2 (MERGED ultra + general, one launch):
// ULTRA path (w_off == 0 AND b_off == 0, the setup distribution): om = 0
//   exactly -> offsets 0, mask = 0.5 exactly; 0.5 folds into BN scale
//   (pow2-exact).  Main loop = plain 3x3 conv via MFMA with:
//   - B-row (4 KB) staged by ONE coalesced glds/wave, double-buffered;
//     kx = px-shift on the LDS read with per-lane edge zero-select.
//   - wave owns {4 ot x 2 pxg}: 18 b128 LDS reads/phase (LDS-BW floor).
//   - epilogue: 2 waves share a px range -> cross-wave sred reduce.
// GENERAL path (R7 structure): full offset conv prologue (w_off != 0) or
//   uniform-offset taps (b_off != 0 only), sampling main loop.
// LDS: sW (48 KB) shared; 13.8 KB overlay union sU4 = {s_ti+s_tw | sB+sred}.
// XCD-swizzled: batch b -> XCD b.
// ---------------------------------------------------------------------------
__global__ __launch_bounds__(256, 2) void k_dcn(
    const unsigned short* __restrict__ xT, const unsigned short* __restrict__ wt,
    const unsigned short* __restrict__ wtoff, const float* __restrict__ b_off,
    const float* __restrict__ vtab, const float* __restrict__ bntab,
    const unsigned int* __restrict__ offflags, float* __restrict__ R) {
  int b = blockIdx.x & 7, row = blockIdx.x >> 3;
  __shared__ unsigned short sW[2 * 12288];   // 49152 B (W dbuf / prologue-A / epi)
  __shared__ float4 sU4[864];                // 13824 B overlay union
  __shared__ unsigned int s_fl[8];
  int t = threadIdx.x, lane = t & 63, wvx = t >> 6;
  int l15 = lane & 15, quad = lane >> 4;
  const unsigned short* xb = xT + (((size_t)b) << 12) * 256;
  const short8 zz = {0, 0, 0, 0, 0, 0, 0, 0};

  // ---- flags --------------------------------------------------------------
  {
    unsigned int a = 0;
    for (int i = t; i < 1152; i += 256) a |= offflags[i];
    unsigned int bo = (lane < 27 && b_off[lane] != 0.f) ? 1u : 0u;
    a = __any(a != 0u) ? 1u : 0u;
    bo = __any(bo != 0u) ? 1u : 0u;
    if (lane == 0) { s_fl[wvx] = a; s_fl[4 + wvx] = bo; }
  }
  __syncthreads();
  const bool offnz = (s_fl[0] | s_fl[1] | s_fl[2] | s_fl[3]) != 0u;
  const bool bofnz = (s_fl[4] | s_fl[5] | s_fl[6] | s_fl[7]) != 0u;

  if (!offnz && !bofnz) {
    // =========================== ULTRA PATH ================================
    unsigned short* sB = (unsigned short*)sU4;             // 2 x 4 KB B-row dbuf
    float* sred = (float*)((char*)sU4 + 8192);             // 64*17 f32 reduce
    int oh = wvx >> 1;                       // ot-half: ot in [oh*4, oh*4+4)
    int ph = wvx & 1;                        // px-half: pxg in {ph*2, ph*2+1}

    floatx4 acc[4][2];
#pragma unroll
    for (int i = 0; i < 4; ++i)
#pragma unroll
      for (int j = 0; j < 2; ++j) acc[i][j] = (floatx4){0.f, 0.f, 0.f, 0.f};

    // prologue: stage W(phase 0) + B-row(phase 0)
#pragma unroll
    for (int i = 0; i < 6; ++i) {
      int blk = wvx * 6 + i;
      glds16(wt + (size_t)blk * 512 + lane * 8, &sW[blk * 512]);
    }
    {   // phase 0: cg=0, kset=0 -> rowk = row-1 (invalid for row 0)
      int rowk = row - 1;
      if (rowk >= 0)
        glds16(xb + (size_t)(rowk * 64 + wvx * 16 + (lane >> 2)) * 256 + (lane & 3) * 8,
               &sB[wvx * 512]);
    }
    __syncthreads();

    for (int phase = 0; phase < 24; ++phase) {
      const unsigned short* bufW = sW + (phase & 1) * 12288;
      const unsigned short* bufB = sB + (phase & 1) * 2048;
      // stage next phase (W 24 KB + B-row 4 KB), overlaps compute below
      if (phase < 23) {
        int np = phase + 1;
        unsigned short* nW = sW + (np & 1) * 12288;
        const unsigned short* wsrc = wt + (size_t)np * 12288;
#pragma unroll
        for (int i = 0; i < 6; ++i) {
          int blk = wvx * 6 + i;
          glds16(wsrc + (size_t)blk * 512 + lane * 8, &nW[blk * 512]);
        }
        int rowk_n = row + np % 3 - 1;
        if ((unsigned)rowk_n < 64u)
          glds16(xb + (size_t)(rowk_n * 64 + wvx * 16 + (lane >> 2)) * 256 +
                     (np / 3) * 32 + (lane & 3) * 8,
                 &sB[((np & 1) * 2048) + wvx * 512]);
      }
      int rowk = row + phase % 3 - 1;
      if ((unsigned)rowk < 64u) {   // invalid row -> contribution exactly 0
#pragma unroll
        for (int kx = 0; kx < 3; ++kx) {
          short8 bf[2];
#pragma unroll
          for (int pg = 0; pg < 2; ++pg) {
            int pxe = (ph * 2 + pg) * 16 + l15 + kx - 1;
            bool v = (unsigned)pxe < 64u;
            int pxc = min(max(pxe, 0), 63);
            union { uint4 u; short8 s; } bb;
            bb.u = *(const uint4*)&bufB[pxc * 32 + quad * 8];
            bf[pg] = v ? bb.s : zz;
          }
          const unsigned short* ak = bufW + kx * 4096 + (oh * 4) * 512 + lane * 8;
#pragma unroll
          for (int oi = 0; oi < 4; ++oi) {
            short8 af = *(const short8*)&ak[oi * 512];
            acc[oi][0] = __builtin_amdgcn_mfma_f32_16x16x32_bf16(af, bf[0], acc[oi][0], 0, 0, 0);
            acc[oi][1] = __builtin_amdgcn_mfma_f32_16x16x32_bf16(af, bf[1], acc[oi][1], 0, 0, 0);
          }
        }
      }
      __syncthreads();  // drains glds(next) + all waves done reading buffers
    }

    // epilogue: BN+ReLU (0.5 folded), v-table contraction, store R
    float* sv = (float*)sW;          // 128*17 vtab (stride 17) + bn
    float* sbn = sv + 2176;
    for (int i = t; i < 2048; i += 256) sv[(i >> 4) * 17 + (i & 15)] = vtab[i];
    if (t < 256) sbn[t] = bntab[t];
    __syncthreads();

    float rpart[2][16];
#pragma unroll
    for (int pg = 0; pg < 2; ++pg)
#pragma unroll
      for (int i = 0; i < 16; ++i) rpart[pg][i] = 0.f;
#pragma unroll
    for (int oi = 0; oi < 4; ++oi)
#pragma unroll
      for (int r = 0; r < 4; ++r) {
        int o = (oh * 4 + oi) * 16 + quad * 4 + r;
        float g = 0.5f * sbn[o], bta = sbn[128 + o];
        const float* vp = &sv[o * 17];
#pragma unroll
        for (int pg = 0; pg < 2; ++pg) {
          float yv = fmaxf(acc[oi][pg][r] * g + bta, 0.f);
#pragma unroll
          for (int tt = 0; tt < 16; ++tt) rpart[pg][tt] += vp[tt] * yv;
        }
      }
#pragma unroll
    for (int pg = 0; pg < 2; ++pg)
#pragma unroll
      for (int tt = 0; tt < 16; ++tt) {
        rpart[pg][tt] += __shfl_xor(rpart[pg][tt], 16, 64);
        rpart[pg][tt] += __shfl_xor(rpart[pg][tt], 32, 64);
      }
    if (oh == 0 && lane < 16) {
#pragma unroll
      for (int pg = 0; pg < 2; ++pg)
#pragma unroll
        for (int tt = 0; tt < 16; ++tt)
          sred[((ph * 2 + pg) * 16 + lane) * 17 + tt] = rpart[pg][tt];
    }
    __syncthreads();
    if (oh == 1 && lane < 16) {
#pragma unroll
      for (int pg = 0; pg < 2; ++pg)
#pragma unroll
        for (int tt = 0; tt < 16; ++tt)
          sred[((ph * 2 + pg) * 16 + lane) * 17 + tt] += rpart[pg][tt];
    }
    __syncthreads();
#pragma unroll
    for (int j = 0; j < 4; ++j) {
      int idx = t + j * 256;
      int slot = idx >> 6, pxs = idx & 63;
      R[(((size_t)(b * 16 + slot)) << 12) + row * 64 + pxs] = sred[pxs * 17 + slot];
    }
    return;
  }

  // ============================ GENERAL PATH ================================
  ushort4* s_ti = (ushort4*)sU4;                       // 576 x 8 B
  float4* s_tw = (float4*)((char*)sU4 + 4608);         // 576 x 16 B
  unsigned short* som = (unsigned short*)s_ti;         // 27*64 bf16 = 3456 B
  int px = wvx * 16 + l15;

  if (!offnz) {
    // warming sweep (b_off-only fast path)
    int wr0 = max(row - 1, 0), wr1 = min(row + 1, 63);
    for (int rr = wr0; rr <= wr1; ++rr) {
      const uint4* src = (const uint4*)(xb + ((size_t)(rr << 6)) * 256);
#pragma unroll
      for (int i = 0; i < 8; ++i) {
        uint4 v = src[t + (i << 8)];
        asm volatile("" :: "v"(v.x), "v"(v.y), "v"(v.z), "v"(v.w));
      }
    }
  }

  // ---- prologue-A (slow path only): offset conv for (b,row) ---------------
  if (offnz) {
    int pixk[9]; bool vkk[9];
#pragma unroll
    for (int k = 0; k < 9; ++k) {
      int yy = row + k / 3 - 1, xx = px + k % 3 - 1;
      vkk[k] = ((unsigned)yy < 64u) & ((unsigned)xx < 64u);
      pixk[k] = vkk[k] ? (yy * 64 + xx) : 0;
    }
    floatx4 oacc[2];
    oacc[0] = (floatx4){0.f, 0.f, 0.f, 0.f};
    oacc[1] = (floatx4){0.f, 0.f, 0.f, 0.f};

#pragma unroll
    for (int i = 0; i < 5; ++i) {
      int frag = wvx + i * 4;
      if (frag < 18)
        glds16(wtoff + (size_t)frag * 512 + lane * 8, &sW[frag * 512]);
    }
    __syncthreads();   // buf0 weights ready

    for (int cg = 0; cg < 8; ++cg) {
      unsigned short* buf = sW + (cg & 1) * 9216;
      int cb = cg * 32 + quad * 8;
      short8 bx[9];
#pragma unroll
      for (int k = 0; k < 9; ++k) {
        short8 v = *(const short8*)&xb[(size_t)pixk[k] * 256 + cb];
        bx[k] = vkk[k] ? v : zz;
      }
      if (cg < 7) {
        const unsigned short* wsrc = wtoff + (size_t)(cg + 1) * 9216;
        unsigned short* nbuf = sW + ((cg + 1) & 1) * 9216;
#pragma unroll
        for (int i = 0; i < 5; ++i) {
          int frag = wvx + i * 4;
          if (frag < 18)
            glds16(wsrc + (size_t)frag * 512 + lane * 8, &nbuf[frag * 512]);
        }
      }
#pragma unroll
      for (int k = 0; k < 9; ++k) {
        short8 a0 = *(const short8*)&buf[(k * 2 + 0) * 512 + lane * 8];
        short8 a1 = *(const short8*)&buf[(k * 2 + 1) * 512 + lane * 8];
        oacc[0] = __builtin_amdgcn_mfma_f32_16x16x32_bf16(a0, bx[k], oacc[0], 0, 0, 0);
        oacc[1] = __builtin_amdgcn_mfma_f32_16x16x32_bf16(a1, bx[k], oacc[1], 0, 0, 0);
      }
      __syncthreads();
    }
#pragma unroll
    for (int ot = 0; ot < 2; ++ot)
#pragma unroll
      for (int r = 0; r < 4; ++r) {
        int o = ot * 16 + quad * 4 + r;
        if (o < 27) som[o * 64 + px] = bf16r(oacc[ot][r] + b_off[o]);
      }
    __syncthreads();   // som complete
  }

  // ---- prologue-B: taps = 4 clamped pixel indices + 4 weights per (k,px) ---
  {
    float to1[3], to2[3], tmv[3];
    if (offnz) {
#pragma unroll
      for (int ii = 0; ii < 3; ++ii) {
        int i = t + ii * 256;
        if (i < 576) {
          int k = i >> 6, p = i & 63;
          to1[ii] = bf2f(som[k * 64 + p]);
          to2[ii] = bf2f(som[(9 + k) * 64 + p]);
          tmv[ii] = bf2f(som[(18 + k) * 64 + p]);
        }
      }
      __syncthreads();   // all som reads done before s_ti overwrites
    } else {
#pragma unroll
      for (int ii = 0; ii < 3; ++ii) {
        int i = t + ii * 256;
        if (i < 576) {
          int k = i >> 6;
          to1[ii] = bf2f(bf16r(b_off[k]));        // == bf16r(0 + b_off)
          to2[ii] = bf2f(bf16r(b_off[9 + k]));
          tmv[ii] = bf2f(bf16r(b_off[18 + k]));
        }
      }
    }
#pragma unroll
    for (int ii = 0; ii < 3; ++ii) {
      int i = t + ii * 256;
      if (i < 576) {
        int k = i >> 6, p = i & 63;
        float m = 1.f / (1.f + __expf(-tmv[ii]));
        float py = (float)(row + k / 3 - 1) + to1[ii];
        float pxf = (float)(p + (k % 3) - 1) + to2[ii];
        float fy = floorf(py), fx = floorf(pxf);
        int iy = (int)fy, ix = (int)fx;
        float wy1 = py - fy, wy0 = 1.f - wy1;
        float wx1 = pxf - fx, wx0 = 1.f - wx1;
        bool y0ok = (iy >= 0) & (iy < 64), y1ok = (iy >= -1) & (iy < 63);
        bool x0ok = (ix >= 0) & (ix < 64), x1ok = (ix >= -1) & (ix < 63);
        int iy0 = min(max(iy, 0), 63), iy1 = min(max(iy + 1, 0), 63);
        int ix0 = min(max(ix, 0), 63), ix1 = min(max(ix + 1, 0), 63);
        s_ti[i] = make_ushort4((unsigned short)(iy0 * 64 + ix0), (unsigned short)(iy0 * 64 + ix1),
                               (unsigned short)(iy1 * 64 + ix0), (unsigned short)(iy1 * 64 + ix1));
        float4 w;
        w.x = (y0ok && x0ok) ? m * wy0 * wx0 : 0.f;
        w.y = (y0ok && x1ok) ? m * wy0 * wx1 : 0.f;
        w.z = (y1ok && x0ok) ? m * wy1 * wx0 : 0.f;
        w.w = (y1ok && x1ok) ? m * wy1 * wx1 : 0.f;
        s_tw[i] = w;
      }
    }
  }
  __syncthreads();   // s_ti/s_tw ready (read-only hereafter)

  const uint4 z4 = make_uint4(0u, 0u, 0u, 0u);

  floatx4 acc[8];
#pragma unroll
  for (int i = 0; i < 8; ++i) acc[i] = (floatx4){0.f, 0.f, 0.f, 0.f};

  uint4 traw[12];   // [kk][tap]
  {
    int cbase = quad * 8;                       // phase 0: cg=0
#pragma unroll
    for (int kk = 0; kk < 3; ++kk) {
      ushort4 ti = s_ti[(kk << 6) + px];        // phase 0: k = kk
      float4 twn = s_tw[(kk << 6) + px];
      uint4 t0 = z4, t1 = z4, t2 = z4, t3 = z4;
      if (__any(twn.x != 0.f)) t0 = *(const uint4*)&xb[(size_t)ti.x * 256 + cbase];
      if (__any(twn.y != 0.f)) t1 = *(const uint4*)&xb[(size_t)ti.y * 256 + cbase];
      if (__any(twn.z != 0.f)) t2 = *(const uint4*)&xb[(size_t)ti.z * 256 + cbase];
      if (__any(twn.w != 0.f)) t3 = *(const uint4*)&xb[(size_t)ti.w * 256 + cbase];
      traw[kk * 4 + 0] = t0; traw[kk * 4 + 1] = t1;
      traw[kk * 4 + 2] = t2; traw[kk * 4 + 3] = t3;
    }
  }
  {  // glds W(phase 0) -> buf 0
    const unsigned short* wsrc = wt;
#pragma unroll
    for (int i = 0; i < 6; ++i) {
      int blk = wvx * 6 + i;
      glds16(wsrc + (size_t)blk * 512 + lane * 8, &sW[blk * 512]);
    }
  }
  __syncthreads();   // buf0 complete (vmcnt drain) + taps in regs

  int lofs = lane * 8;   // lane-linear A-frag offset (ushorts)

  for (int phase = 0; phase < 24; ++phase) {
    unsigned short* buf = sW + (phase & 1) * 12288;
    unsigned short* nbuf = sW + ((phase + 1) & 1) * 12288;
    if (phase < 23) {
      const unsigned short* wsrc = wt + (size_t)(phase + 1) * 12288;
#pragma unroll
      for (int i = 0; i < 6; ++i) {
        int blk = wvx * 6 + i;
        glds16(wsrc + (size_t)blk * 512 + lane * 8, &nbuf[blk * 512]);
      }
    }
    int nphase = phase + 1;
    int ncbase = (nphase / 3) * 32 + quad * 8;

#pragma unroll
    for (int kk = 0; kk < 3; ++kk) {
      int k = (phase % 3) * 3 + kk;
      float4 tw = s_tw[(k << 6) + px];
      union { uint4 u; short8 s; } x0, x1, x2, x3;
      x0.u = traw[kk * 4 + 0]; x1.u = traw[kk * 4 + 1];
      x2.u = traw[kk * 4 + 2]; x3.u = traw[kk * 4 + 3];
      if (phase < 23) {
        int nk = (nphase % 3) * 3 + kk;
        ushort4 ti = s_ti[(nk << 6) + px];
        float4 twn = s_tw[(nk << 6) + px];
        uint4 t0 = z4, t1 = z4, t2 = z4, t3 = z4;
        if (__any(twn.x != 0.f)) t0 = *(const uint4*)&xb[(size_t)ti.x * 256 + ncbase];
        if (__any(twn.y != 0.f)) t1 = *(const uint4*)&xb[(size_t)ti.y * 256 + ncbase];
        if (__any(twn.z != 0.f)) t2 = *(const uint4*)&xb[(size_t)ti.z * 256 + ncbase];
        if (__any(twn.w != 0.f)) t3 = *(const uint4*)&xb[(size_t)ti.w * 256 + ncbase];
        traw[kk * 4 + 0] = t0; traw[kk * 4 + 1] = t1;
        traw[kk * 4 + 2] = t2; traw[kk * 4 + 3] = t3;
      }
      float r[8];
#pragma unroll
      for (int j = 0; j < 8; ++j) r[j] = tw.x * bf2f((unsigned short)x0.s[j]);
      if (__any(tw.y != 0.f)) {
#pragma unroll
        for (int j = 0; j < 8; ++j) r[j] += tw.y * bf2f((unsigned short)x1.s[j]);
      }
      if (__any(tw.z != 0.f)) {
#pragma unroll
        for (int j = 0; j < 8; ++j) r[j] += tw.z * bf2f((unsigned short)x2.s[j]);
      }
      if (__any(tw.w != 0.f)) {
#pragma unroll
        for (int j = 0; j < 8; ++j) r[j] += tw.w * bf2f((unsigned short)x3.s[j]);
      }
      union { uint4 u; short8 s; } bu;
      bu.u = make_uint4(bf16h(r[0]) | (bf16h(r[1]) << 16), bf16h(r[2]) | (bf16h(r[3]) << 16),
                        bf16h(r[4]) | (bf16h(r[5]) << 16), bf16h(r[6]) | (bf16h(r[7]) << 16));
      const unsigned short* bk = buf + kk * 4096 + lofs;
#pragma unroll
      for (int ot = 0; ot < 8; ++ot) {
        short8 af = *(const short8*)&bk[ot * 512];
        acc[ot] = __builtin_amdgcn_mfma_f32_16x16x32_bf16(af, bu.s, acc[ot], 0, 0, 0);
      }
    }
    __syncthreads();  // drains glds(next) + all waves done reading buf
  }

  // epilogue: BN+ReLU then R[slot][px] = sum_o v[o][slot]*yv, reduced over quads
  float* sv = (float*)sW;          // 128*17 vtab (stride 17: conflict-free) + bn
  float* sbn = sv + 2176;
  for (int i = t; i < 2048; i += 256) sv[(i >> 4) * 17 + (i & 15)] = vtab[i];
  if (t < 256) sbn[t] = bntab[t];
  __syncthreads();

  float rpart[16];
#pragma unroll
  for (int i = 0; i < 16; ++i) rpart[i] = 0.f;
#pragma unroll
  for (int ot = 0; ot < 8; ++ot)
#pragma unroll
    for (int r = 0; r < 4; ++r) {
      int o = ot * 16 + quad * 4 + r;
      float yv = fmaxf(acc[ot][r] * sbn[o] + sbn[128 + o], 0.f);
      const float* vp = &sv[o * 17];
#pragma unroll
      for (int tt = 0; tt < 16; ++tt) rpart[tt] += vp[tt] * yv;
    }
#pragma unroll
  for (int tt = 0; tt < 16; ++tt) {
    rpart[tt] += __shfl_xor(rpart[tt], 16, 64);
    rpart[tt] += __shfl_xor(rpart[tt], 32, 64);
  }
#pragma unroll
  for (int j = 0; j < 4; ++j) {
    int slot = quad * 4 + j;
    R[(((size_t)(b * 16 + slot)) << 12) + row * 64 + px] = rpart[slot];
  }
}

// ---------------------------------------------------------------------------
// K3: upsample+1x1+sigmoid from R planes: 4 coalesced loads + sigmoid
// ---------------------------------------------------------------------------
__global__ __launch_bounds__(256) void k_upb(
    const float* __restrict__ R, float* __restrict__ out) {
  int b = blockIdx.x & 7, sub = blockIdx.x >> 3;
  int inner = sub * 256 + threadIdx.x;        // 0..16383
  int X = inner & 127, Y = inner >> 7;        // Y 0..127
  int i0, wu0, wu1, j0, wv0, wv1;
  if (Y & 1) { i0 = (Y - 1) >> 1; wu0 = 2; wu1 = 0; }
  else       { i0 = (Y - 2) / 2;  wu0 = 3; wu1 = 1; }
  if (X & 1) { j0 = (X - 1) >> 1; wv0 = 2; wv1 = 0; }
  else       { j0 = (X - 2) / 2;  wv0 = 3; wv1 = 1; }
  int i1 = i0 + 1, j1 = j0 + 1;
  float mi0 = ((unsigned)i0 < 64u) ? 1.f : 0.f;
  float mi1 = ((unsigned)i1 < 64u) ? 1.f : 0.f;
  float mj0 = ((unsigned)j0 < 64u) ? 1.f : 0.f;
  float mj1 = ((unsigned)j1 < 64u) ? 1.f : 0.f;
  int i0c = min(max(i0, 0), 63), i1c = min(max(i1, 0), 63);
  int j0c = min(max(j0, 0), 63), j1c = min(max(j1, 0), 63);
  const float* Rb = R + (((size_t)b) << 16);   // b*16*4096
  float s = mi0 * mj0 * Rb[((wu0 * 4 + wv0) << 12) + (i0c << 6) + j0c] +
            mi0 * mj1 * Rb[((wu0 * 4 + wv1) << 12) + (i0c << 6) + j1c] +
            mi1 * mj0 * Rb[((wu1 * 4 + wv0) << 12) + (i1c << 6) + j0c] +
            mi1 * mj1 * Rb[((wu1 * 4 + wv1) << 12) + (i1c << 6) + j1c];
  out[(b << 14) + inner] = 1.f / (1.f + __expf(-s));
}

// ---------------------------------------------------------------------------
extern "C" void kernel_launch(void* const* d_in, const int* in_sizes, int n_in,
                              void* d_out, int out_size, void* d_ws, size_t ws_size,
                              hipStream_t stream) {
  const float* x        = (const float*)d_in[0];
  const float* w_dcn    = (const float*)d_in[1];
  const float* b_dcn    = (const float*)d_in[2];
  const float* w_off    = (const float*)d_in[3];
  const float* b_off    = (const float*)d_in[4];
  const float* bn_gamma = (const float*)d_in[5];
  const float* bn_beta  = (const float*)d_in[6];
  const float* bn_mean  = (const float*)d_in[7];
  const float* bn_var   = (const float*)d_in[8];
  const float* w_up     = (const float*)d_in[9];
  const float* w_1x1    = (const float*)d_in[10];
  float* out = (float*)d_out;

  // ws layout in FLOAT units:
  float* ws = (float*)d_ws;
  unsigned short* xT     = (unsigned short*)ws;                    // 8388608 ush
  unsigned short* wt_dcn = (unsigned short*)(ws + 4194304);        //  294912 ush
  unsigned short* wt_off = (unsigned short*)(ws + 4341760);        //   73728 ush
  float* vtab            = ws + 4378624;                           //    2048 f
  float* bntab           = ws + 4380672;                           //     256 f
  unsigned int* offflags = (unsigned int*)(ws + 4380928);          //    1152 u32
  float* R               = ws + 4823296;                           //  524288 f

  k_pre<<<1152, 256, 0, stream>>>(x, w_dcn, w_off, b_dcn, bn_gamma, bn_beta,
                                  bn_mean, bn_var, w_up, w_1x1,
                                  xT, wt_dcn, wt_off, vtab, bntab, offflags);
  k_dcn<<<512, 256, 0, stream>>>(xT, wt_dcn, wt_off, b_off, vtab, bntab,
                                 offflags, R);
  k_upb<<<512, 256, 0, stream>>>(R, out);
}